// Round 7
// baseline (193.187 us; speedup 1.0000x reference)
//
#include <hip/hip_runtime.h>
#include <hip/hip_bf16.h>
#include <math.h>

#define NB 2
#define NHH 16
#define TT 1024
#define HDD 64
#define NSS 3
#define HH 1024
#define MMR 2048  // NB*TT

typedef float f4 __attribute__((ext_vector_type(4)));
typedef short bf16x8 __attribute__((ext_vector_type(8)));
typedef unsigned short u16;
typedef u16 u16x4 __attribute__((ext_vector_type(4)));

__device__ inline u16 f2bf(float f) {
    union { float f; unsigned u; } v; v.f = f;
    unsigned r = (v.u + 0x7FFFu + ((v.u >> 16) & 1u)) >> 16;
    return (u16)r;
}
__device__ inline float bf2f(u16 u) {
    union { unsigned u; float f; } v; v.u = ((unsigned)u) << 16;
    return v.f;
}

__device__ inline float red16sum(float v) {
    v += __shfl_xor(v, 1);
    v += __shfl_xor(v, 2);
    v += __shfl_xor(v, 4);
    v += __shfl_xor(v, 8);
    return v;
}
__device__ inline float red64sum(float v) {
    v += __shfl_xor(v, 1);
    v += __shfl_xor(v, 2);
    v += __shfl_xor(v, 4);
    v += __shfl_xor(v, 8);
    v += __shfl_xor(v, 16);
    v += __shfl_xor(v, 32);
    return v;
}

// ------ fused fp32->bf16 convert: hs, W1, W2, keys(x0.125) + keys passthrough ------
__global__ __launch_bounds__(256) void k_cvt4(const float* __restrict__ s0, u16* __restrict__ d0,
                                              const float* __restrict__ s1, u16* __restrict__ d1,
                                              const float* __restrict__ s2, u16* __restrict__ d2,
                                              const float* __restrict__ s3, u16* __restrict__ d3,
                                              float* __restrict__ outk) {
    int b = blockIdx.x;
    if (b >= 4096) {  // keys: scale 1/8 into k_b (align term rescaled by 8 in k_attn)
        int i = (b - 4096) * 256 + threadIdx.x;
        f4 v = ((const f4*)s3)[i];
        ((f4*)outk)[i] = v;  // passthrough copy to out
        u16x4 o;
        o[0] = f2bf(v[0] * 0.125f); o[1] = f2bf(v[1] * 0.125f);
        o[2] = f2bf(v[2] * 0.125f); o[3] = f2bf(v[3] * 0.125f);
        ((u16x4*)d3)[i] = o;
        return;
    }
    const float* s; u16* d; int base;
    if (b < 2048)      { s = s0; d = d0; base = 0; }
    else if (b < 3072) { s = s1; d = d1; base = 2048; }
    else               { s = s2; d = d2; base = 3072; }
    int i = (b - base) * 256 + threadIdx.x;
    f4 v = ((const f4*)s)[i];
    u16x4 o;
    o[0] = f2bf(v[0]); o[1] = f2bf(v[1]); o[2] = f2bf(v[2]); o[3] = f2bf(v[3]);
    ((u16x4*)d)[i] = o;
}

// ------ V transpose: [BH,T,64] f32 -> [BH,64,T] bf16, + values passthrough ------
__global__ __launch_bounds__(256) void k_vtrans(const float* __restrict__ V,
                                                u16* __restrict__ Vt,
                                                float* __restrict__ outv) {
    __shared__ float tile[64][65];
    int bh = blockIdx.y, t0 = blockIdx.x * 64;
    int r = threadIdx.x >> 2, c0 = (threadIdx.x & 3) * 16;
    const float* vp = V + ((size_t)bh * TT + t0) * HDD;
#pragma unroll
    for (int j = 0; j < 16; j += 4) {
        f4 v = *(const f4*)(vp + r * HDD + c0 + j);
        tile[r][c0 + j + 0] = v[0]; tile[r][c0 + j + 1] = v[1];
        tile[r][c0 + j + 2] = v[2]; tile[r][c0 + j + 3] = v[3];
        *(f4*)(outv + ((size_t)bh * TT + t0 + r) * HDD + c0 + j) = v;
    }
    __syncthreads();
    int d = threadIdx.x >> 2, x0 = (threadIdx.x & 3) * 16;
    u16* op = Vt + ((size_t)bh * HDD + d) * TT + t0 + x0;
#pragma unroll
    for (int j = 0; j < 16; j += 4) {
        u16x4 o;
        o[0] = f2bf(tile[x0 + j + 0][d]); o[1] = f2bf(tile[x0 + j + 1][d]);
        o[2] = f2bf(tile[x0 + j + 2][d]); o[3] = f2bf(tile[x0 + j + 3][d]);
        *(u16x4*)(op + j) = o;
    }
}

// ---------------- GEMM: C[M,N] = A[M,K] * B[N,K]^T + bias ----------------
// EPI 0: out row-major [M,N] fp32.
// EPI 1: out = A5*que + CC*(acc+bias) scattered to [B,NH,T,HD]  (PCN base).
template <int EPI>
__global__ __launch_bounds__(256) void k_gemm_bt(const u16* __restrict__ A,
                                                 const u16* __restrict__ Bm,
                                                 const float* __restrict__ bias,
                                                 const float* __restrict__ que,
                                                 float* __restrict__ out) {
    const int K = 1024, N = 1024;
    int w = threadIdx.x >> 6, l = threadIdx.x & 63, lr = l & 15, lg = l >> 4;
    int m0 = blockIdx.y * 64 + w * 16;
    int n0 = blockIdx.x * 64;
    const u16* ap = A + (size_t)(m0 + lr) * K + lg * 8;
    const u16* bp = Bm + (size_t)(n0 + lr) * K + lg * 8;
    f4 z4 = {0.f, 0.f, 0.f, 0.f};
    f4 acc[4] = {z4, z4, z4, z4};
#pragma unroll 2
    for (int kk = 0; kk < K; kk += 32) {
        bf16x8 a  = *(const bf16x8*)(ap + kk);
        bf16x8 b0 = *(const bf16x8*)(bp + kk);
        bf16x8 b1 = *(const bf16x8*)(bp + 16 * K + kk);
        bf16x8 b2 = *(const bf16x8*)(bp + 32 * K + kk);
        bf16x8 b3 = *(const bf16x8*)(bp + 48 * K + kk);
        acc[0] = __builtin_amdgcn_mfma_f32_16x16x32_bf16(a, b0, acc[0], 0, 0, 0);
        acc[1] = __builtin_amdgcn_mfma_f32_16x16x32_bf16(a, b1, acc[1], 0, 0, 0);
        acc[2] = __builtin_amdgcn_mfma_f32_16x16x32_bf16(a, b2, acc[2], 0, 0, 0);
        acc[3] = __builtin_amdgcn_mfma_f32_16x16x32_bf16(a, b3, acc[3], 0, 0, 0);
    }
    const float A5 = 0.9509900499f, CC = 1.0f - A5;
#pragma unroll
    for (int cf = 0; cf < 4; ++cf) {
        int col = n0 + cf * 16 + lr;
        float bs = bias[col];
#pragma unroll
        for (int r = 0; r < 4; ++r) {
            int row = m0 + lg * 4 + r;
            float v = acc[cf][r] + bs;
            if (EPI == 0) {
                out[(size_t)row * N + col] = v;
            } else {
                int b = row >> 10, t = row & 1023, nh = col >> 6, hd = col & 63;
                size_t oidx = (((size_t)(b * NHH + nh)) * TT + t) * HDD + hd;
                out[oidx] = A5 * que[oidx] + CC * v;
            }
        }
    }
}

// ---------------- LayerNorm + ReLU -> bf16 ----------------
__global__ __launch_bounds__(256) void k_lnrelu(const float* __restrict__ X,
                                                const float* __restrict__ g,
                                                const float* __restrict__ bta,
                                                u16* __restrict__ xr) {
    int row = blockIdx.x;
    f4 v = ((const f4*)(X + (size_t)row * HH))[threadIdx.x];
    float s = v[0] + v[1] + v[2] + v[3];
    float s2 = v[0] * v[0] + v[1] * v[1] + v[2] * v[2] + v[3] * v[3];
    s = red64sum(s);
    s2 = red64sum(s2);
    __shared__ float red[8];
    int w = threadIdx.x >> 6, l = threadIdx.x & 63;
    if (l == 0) { red[w] = s; red[w + 4] = s2; }
    __syncthreads();
    float S1 = red[0] + red[1] + red[2] + red[3];
    float S2 = red[4] + red[5] + red[6] + red[7];
    float mu = S1 * (1.0f / 1024.0f);
    float var = S2 * (1.0f / 1024.0f) - mu * mu;
    float rstd = rsqrtf(var + 1e-5f);
    f4 gv = ((const f4*)g)[threadIdx.x];
    f4 bv = ((const f4*)bta)[threadIdx.x];
    u16x4 o;
#pragma unroll
    for (int j = 0; j < 4; ++j) {
        float y = (v[j] - mu) * rstd * gv[j] + bv[j];
        y = fmaxf(y, 0.f);
        o[j] = f2bf(y);
    }
    ((u16x4*)(xr + (size_t)row * HH))[threadIdx.x] = o;
}

// ------- fused q-formation + flash attention + energy stats -------
// 64 q-rows/block, 1536 blocks (6/CU), XCD-colocated per (b,h).
// q = base + CH*hyp_s + sum_k C_k*rn_{s,k}  (base = A5*que+CC*ctx from GEMM2).
// Swapped QK^T (mfma(K,Q)): lane holds S[q=lr][k=cf*16+lg*4+r]; exp ->
// cvt_pk_bf16 pairs -> xor-32/16 butterfly into PV A-frag layout (no LDS).
// align extracted from QK diagonal at kt==qt (S[t][t]*8). Max-free softmax.
__global__ __launch_bounds__(256, 6) void k_attn(const float* __restrict__ basep_,
                                                 const float* __restrict__ hyp,
                                                 const float* __restrict__ rn,
                                                 const u16* __restrict__ Kb,
                                                 const u16* __restrict__ Vt,
                                                 u16* __restrict__ qq,
                                                 float* __restrict__ part) {
    int bi = blockIdx.x;
    int p_ = bi & 31, j_ = bi >> 5;          // XCD swizzle: (b,h) = bi%32
    int h = p_ & 15, b = p_ >> 4;
    int s = j_ >> 4, qt = j_ & 15;
    int sb = s * 2 + b;
    int bh = b * NHH + h;
    int pi = sb * 256 + h * 16 + qt;         // part index, contiguous per sb
    int w = threadIdx.x >> 6, l = threadIdx.x & 63, lr = l & 15, lg = l >> 4;
    int b4 = (l >> 4) & 1, b5 = (l >> 5) & 1;
    int t0 = qt * 64;
    f4 z4 = {0.f, 0.f, 0.f, 0.f};

    __shared__ u16 Ks[4096];        // 64x64, byte ^= ((row&7)<<4)
    __shared__ u16 Vs[4096];

    // ---- fused q formation in fragment layout ----
    const float CH = 0.1f * 0.9509900499f;
    const float C0 = 0.0096059601f, C1 = 0.0097029900f, C2 = 0.0098010000f, C3 = 0.0099f;
    const float* basep = basep_ + ((size_t)bh * TT) * HDD;
    const float* hypp = hyp + ((size_t)(sb * NHH + h) * TT) * HDD;
    const float* rn0p = rn + ((size_t)(((s * 4 + 0) * 2 + b) * NHH + h) * TT) * HDD;
    const float* rn1p = rn + ((size_t)(((s * 4 + 1) * 2 + b) * NHH + h) * TT) * HDD;
    const float* rn2p = rn + ((size_t)(((s * 4 + 2) * 2 + b) * NHH + h) * TT) * HDD;
    const float* rn3p = rn + ((size_t)(((s * 4 + 3) * 2 + b) * NHH + h) * TT) * HDD;
    u16* qqp = qq + ((size_t)(sb * NHH + h) * TT) * HDD;

    bf16x8 aq[2];
    {
        size_t ro = (size_t)(t0 + w * 16 + lr) * HDD;
#pragma unroll
        for (int c = 0; c < 2; ++c) {
            int d0 = c * 32 + lg * 8;
            f4 va, vb;
#pragma unroll
            for (int half = 0; half < 2; ++half) {
                size_t off = ro + d0 + half * 4;
                f4 v = *(const f4*)(basep + off);
                v += CH * __builtin_nontemporal_load((const f4*)(hypp + off));
                v += C0 * __builtin_nontemporal_load((const f4*)(rn0p + off));
                v += C1 * __builtin_nontemporal_load((const f4*)(rn1p + off));
                v += C2 * __builtin_nontemporal_load((const f4*)(rn2p + off));
                v += C3 * __builtin_nontemporal_load((const f4*)(rn3p + off));
                if (half == 0) va = v; else vb = v;
            }
            union { bf16x8 f; u16 u[8]; int4 i4; } o;
#pragma unroll
            for (int j = 0; j < 4; ++j) { o.u[j] = f2bf(va[j]); o.u[4 + j] = f2bf(vb[j]); }
            aq[c] = o.f;
            *(int4*)(qqp + ro + d0) = o.i4;   // for k_select
        }
    }

    // staging addresses (thread covers 16B units u and u+256 of each 8KB tile)
    const u16* kbase = Kb + (size_t)bh * TT * HDD;
    const u16* vbase = Vt + (size_t)bh * HDD * TT;
    int u0 = threadIdx.x, u1 = threadIdx.x + 256;
    const u16* kg0 = kbase + u0 * 8;
    const u16* kg1 = kbase + u1 * 8;
    const u16* vg0 = vbase + (size_t)(u0 >> 3) * TT + (u0 & 7) * 8;
    const u16* vg1 = vbase + (size_t)(u1 >> 3) * TT + (u1 & 7) * 8;
    int ko0 = (u0 >> 3) * 128 + (((u0 & 7) ^ ((u0 >> 3) & 7)) << 4);
    int ko1 = (u1 >> 3) * 128 + (((u1 & 7) ^ ((u1 >> 3) & 7)) << 4);
    char* KsB = (char*)Ks;
    char* VsB = (char*)Vs;

    int4 kr0 = *(const int4*)(kg0);
    int4 kr1 = *(const int4*)(kg1);
    int4 vr0 = *(const int4*)(vg0);
    int4 vr1 = *(const int4*)(vg1);

    f4 acco[4] = {z4, z4, z4, z4};
    float zacc = 0.f, wacc = 0.f, al_lane = 0.f;

    for (int kt = 0; kt < 16; ++kt) {
        __syncthreads();  // previous tile's reads complete
        *(int4*)(KsB + ko0) = kr0;
        *(int4*)(KsB + ko1) = kr1;
        *(int4*)(VsB + ko0) = vr0;
        *(int4*)(VsB + ko1) = vr1;
        if (kt < 15) {  // issue next-tile loads; latency hides under compute
            kr0 = *(const int4*)(kg0 + (kt + 1) * 4096);
            kr1 = *(const int4*)(kg1 + (kt + 1) * 4096);
            vr0 = *(const int4*)(vg0 + (kt + 1) * 64);
            vr1 = *(const int4*)(vg1 + (kt + 1) * 64);
        }
        __syncthreads();  // tile visible

        // swapped QK^T: st[cf][r] = S[q=lr][k=kt*64+cf*16+lg*4+r]
        f4 st[4];
#pragma unroll
        for (int cf = 0; cf < 4; ++cf) {
            int row = cf * 16 + lr, rs = row & 7;
            bf16x8 bk0 = *(const bf16x8*)(KsB + row * 128 + ((lg ^ rs) << 4));
            bf16x8 bk1 = *(const bf16x8*)(KsB + row * 128 + (((4 + lg) ^ rs) << 4));
            f4 t0a = __builtin_amdgcn_mfma_f32_16x16x32_bf16(bk0, aq[0], z4, 0, 0, 0);
            st[cf] = __builtin_amdgcn_mfma_f32_16x16x32_bf16(bk1, aq[1], t0a, 0, 0, 0);
        }

        // align from diagonal: q-row t0+w*16+lr meets k==row at kt==qt, cf==w,
        // lane group lg==lr>>2, element r==lr&3. S includes the 1/8 scale -> x8.
        if (kt == qt) {
            f4 stw = w == 0 ? st[0] : (w == 1 ? st[1] : (w == 2 ? st[2] : st[3]));
            int rr = lr & 3;
            float dsel = rr == 0 ? stw[0] : (rr == 1 ? stw[1] : (rr == 2 ? stw[2] : stw[3]));
            if (lg == (lr >> 2)) al_lane += dsel * 8.0f;
        }

        // exp + pack + butterfly -> PV A-frags (no LDS)
        bf16x8 pa[2];
        {
            unsigned pk[4][2];
            float zp = 0.f, wp = 0.f;
#pragma unroll
            for (int cf = 0; cf < 4; ++cf) {
                float p0 = __expf(st[cf][0]);
                float p1 = __expf(st[cf][1]);
                float p2 = __expf(st[cf][2]);
                float p3 = __expf(st[cf][3]);
                zp += (p0 + p1) + (p2 + p3);
                wp = fmaf(p0, st[cf][0], wp);
                wp = fmaf(p1, st[cf][1], wp);
                wp = fmaf(p2, st[cf][2], wp);
                wp = fmaf(p3, st[cf][3], wp);
                asm("v_cvt_pk_bf16_f32 %0, %1, %2" : "=v"(pk[cf][0]) : "v"(p0), "v"(p1));
                asm("v_cvt_pk_bf16_f32 %0, %1, %2" : "=v"(pk[cf][1]) : "v"(p2), "v"(p3));
            }
            zacc += zp;
            wacc += wp;
            // step 1: xor 32 — keep items with cf&1 == b5
            unsigned keep0[2][2], got0[2][2];
#pragma unroll
            for (int ch = 0; ch < 2; ++ch)
#pragma unroll
                for (int wi = 0; wi < 2; ++wi) {
                    unsigned own  = b5 ? pk[2 * ch + 1][wi] : pk[2 * ch][wi];
                    unsigned send = b5 ? pk[2 * ch][wi]     : pk[2 * ch + 1][wi];
                    keep0[ch][wi] = own;
                    got0[ch][wi]  = (unsigned)__shfl_xor((int)send, 32);
                }
            // step 2: xor 16 — keep items with src_b5' == b4, order by src_b4'
            union { unsigned u[4]; bf16x8 f; } pc[2];
#pragma unroll
            for (int ch = 0; ch < 2; ++ch)
#pragma unroll
                for (int wi = 0; wi < 2; ++wi) {
                    unsigned own2  = (b5 == b4) ? keep0[ch][wi] : got0[ch][wi];
                    unsigned send2 = (b5 == b4) ? got0[ch][wi]  : keep0[ch][wi];
                    unsigned got2  = (unsigned)__shfl_xor((int)send2, 16);
                    pc[ch].u[wi]     = b4 ? got2 : own2;
                    pc[ch].u[2 + wi] = b4 ? own2 : got2;
                }
            pa[0] = pc[0].f;
            pa[1] = pc[1].f;
        }

        // PV
#pragma unroll
        for (int cf = 0; cf < 4; ++cf) {
            int row = cf * 16 + lr, rs = row & 7;
            bf16x8 bv0 = *(const bf16x8*)(VsB + row * 128 + ((lg ^ rs) << 4));
            bf16x8 bv1 = *(const bf16x8*)(VsB + row * 128 + (((4 + lg) ^ rs) << 4));
            acco[cf] = __builtin_amdgcn_mfma_f32_16x16x32_bf16(pa[0], bv0, acco[cf], 0, 0, 0);
            acco[cf] = __builtin_amdgcn_mfma_f32_16x16x32_bf16(pa[1], bv1, acco[cf], 0, 0, 0);
        }
    }

    // finalize: z/w per-lane for q-row lr; acco rows are q=lg*4+r
    float zf = zacc;
    zf += __shfl_xor(zf, 16); zf += __shfl_xor(zf, 32);
    float wf = wacc;
    wf += __shfl_xor(wf, 16); wf += __shfl_xor(wf, 32);
    float ent_lane = __logf(zf) - wf / zf;         // row lr, 4 lg-copies
    float mag_lane = 0.f;
#pragma unroll
    for (int r = 0; r < 4; ++r) {
        float ssq = acco[0][r] * acco[0][r] + acco[1][r] * acco[1][r] +
                    acco[2][r] * acco[2][r] + acco[3][r] * acco[3][r];
        ssq = red16sum(ssq);                       // row lg*4+r, 16 copies
        float zq = __shfl(zf, lg * 4 + r);
        mag_lane += sqrtf(ssq) / zq;
    }
    float magw = red64sum(mag_lane) * (1.0f / 16.0f);
    float entw = red64sum(ent_lane) * 0.25f;
    float al   = red64sum(al_lane);

    __shared__ float red[4][3];
    if (l == 0) { red[w][0] = magw; red[w][1] = entw; red[w][2] = al; }
    __syncthreads();
    if (threadIdx.x == 0) {
        part[pi * 3 + 0] = red[0][0] + red[1][0] + red[2][0] + red[3][0];
        part[pi * 3 + 1] = red[0][1] + red[1][1] + red[2][1] + red[3][1];
        part[pi * 3 + 2] = red[0][2] + red[1][2] + red[2][2] + red[3][2];
    }
}

// ---------------- energy reduce + softmax over samples ----------------
__global__ void k_finalize(const float* __restrict__ part, float* __restrict__ probs) {
    int w = threadIdx.x >> 6, l = threadIdx.x & 63;
    __shared__ float eng[6];
    if (w < 6) {
        float a0 = 0.f, a1 = 0.f, a2 = 0.f;
        for (int i = l; i < 256; i += 64) {
            const float* pp = part + (size_t)(w * 256 + i) * 3;
            a0 += pp[0]; a1 += pp[1]; a2 += pp[2];
        }
        a0 = red64sum(a0); a1 = red64sum(a1); a2 = red64sum(a2);
        if (l == 0) {
            const float inv = 1.0f / 16384.0f;
            eng[w] = a0 * inv - 0.1f * (a1 * inv) - 0.05f * (a2 * inv);
        }
    }
    __syncthreads();
    if (threadIdx.x < 2) {
        int b = threadIdx.x;
        float e0 = -eng[0 + b], e1 = -eng[2 + b], e2 = -eng[4 + b];
        float mx = fmaxf(e0, fmaxf(e1, e2));
        float x0 = __expf(e0 - mx), x1 = __expf(e1 - mx), x2 = __expf(e2 - mx);
        float inv = 1.0f / (x0 + x1 + x2);
        probs[0 + b] = x0 * inv;
        probs[2 + b] = x1 * inv;
        probs[4 + b] = x2 * inv;
    }
}

// ---------------- selected = sum_s probs[s,b]*q[s] (q in bf16) ----------------
__global__ __launch_bounds__(256) void k_select(const u16* __restrict__ qq,
                                                const float* __restrict__ probs,
                                                float* __restrict__ out) {
    const int NQ4 = 524288;               // u16x4 groups per sample
    int i = blockIdx.x * 256 + threadIdx.x;
    int b = i >> 18;                      // 262144 groups per batch
    float p0 = probs[0 + b], p1 = probs[2 + b], p2 = probs[4 + b];
    u16x4 a0 = ((const u16x4*)qq)[i];
    u16x4 a1 = ((const u16x4*)qq)[NQ4 + i];
    u16x4 a2 = ((const u16x4*)qq)[2 * NQ4 + i];
    f4 v;
#pragma unroll
    for (int j = 0; j < 4; ++j)
        v[j] = p0 * bf2f(a0[j]) + p1 * bf2f(a1[j]) + p2 * bf2f(a2[j]);
    ((f4*)out)[i] = v;
}

extern "C" void kernel_launch(void* const* d_in, const int* in_sizes, int n_in,
                              void* d_out, int out_size, void* d_ws, size_t ws_size,
                              hipStream_t stream) {
    const float* queries = (const float*)d_in[0];
    const float* keys    = (const float*)d_in[1];
    const float* values  = (const float*)d_in[2];
    const float* hs      = (const float*)d_in[3];
    const float* W1      = (const float*)d_in[4];
    const float* b1      = (const float*)d_in[5];
    const float* ln_g    = (const float*)d_in[6];
    const float* ln_b    = (const float*)d_in[7];
    const float* W2      = (const float*)d_in[8];
    const float* b2      = (const float*)d_in[9];
    const float* hyp     = (const float*)d_in[10];
    const float* rn      = (const float*)d_in[11];
    float* out = (float*)d_out;
    char* ws = (char*)d_ws;

    const size_t MB = 1024ull * 1024ull;
    // qq16 occupies [0,12MB); MLP temporaries overlap it (all dead before k_attn)
    u16*   qq16 = (u16*)(ws);                   // 12 MB  [S,B,NH,T,HD] bf16
    u16*   hs_b = (u16*)(ws + 0 * MB);          //  4 MB  (dead after gemm1)
    u16*   w1_b = (u16*)(ws + 4 * MB);          //  2 MB  (dead after gemm1)
    u16*   w2_b = (u16*)(ws + 6 * MB);          //  2 MB  (dead after gemm2)
    float* X    = (float*)(ws + 8 * MB);        //  8 MB  (dead after lnrelu)
    u16*   xr   = (u16*)(ws + 16 * MB);         //  4 MB  (dead after gemm2)
    float* base = (float*)(ws + 24 * MB);       //  8 MB  (A5*que + CC*ctx)
    u16*   k_b  = (u16*)(ws + 32 * MB);         //  4 MB  (keys * 0.125, bf16)
    u16*   vt_b = (u16*)(ws + 36 * MB);         //  4 MB
    float* part = (float*)(ws + 40 * MB);       // 18 KB
    float* probs= (float*)(ws + 40 * MB + 65536);

    k_cvt4<<<6144, 256, 0, stream>>>(hs, hs_b, W1, w1_b, W2, w2_b, keys, k_b,
                                     out + 2097152);
    k_vtrans<<<dim3(16, 32), 256, 0, stream>>>(values, vt_b, out + 4194304);

    k_gemm_bt<0><<<dim3(16, 32), 256, 0, stream>>>(hs_b, w1_b, b1, nullptr, X);
    k_lnrelu<<<2048, 256, 0, stream>>>(X, ln_g, ln_b, xr);
    k_gemm_bt<1><<<dim3(16, 32), 256, 0, stream>>>(xr, w2_b, b2, queries, base);

    k_attn<<<1536, 256, 0, stream>>>(base, hyp, rn, k_b, vt_b, qq16, part);
    k_finalize<<<1, 384, 0, stream>>>(part, probs);
    k_select<<<2048, 256, 0, stream>>>(qq16, probs, out);
}

// Round 8
// 172.515 us; speedup vs baseline: 1.1198x; 1.1198x over previous
//
#include <hip/hip_runtime.h>
#include <hip/hip_bf16.h>
#include <math.h>

#define NB 2
#define NHH 16
#define TT 1024
#define HDD 64
#define NSS 3
#define HH 1024
#define MMR 2048  // NB*TT

typedef float f4 __attribute__((ext_vector_type(4)));
typedef short bf16x8 __attribute__((ext_vector_type(8)));
typedef unsigned short u16;
typedef u16 u16x4 __attribute__((ext_vector_type(4)));

__device__ inline u16 f2bf(float f) {
    union { float f; unsigned u; } v; v.f = f;
    unsigned r = (v.u + 0x7FFFu + ((v.u >> 16) & 1u)) >> 16;
    return (u16)r;
}
__device__ inline float bf2f(u16 u) {
    union { unsigned u; float f; } v; v.u = ((unsigned)u) << 16;
    return v.f;
}

__device__ inline float red16sum(float v) {
    v += __shfl_xor(v, 1);
    v += __shfl_xor(v, 2);
    v += __shfl_xor(v, 4);
    v += __shfl_xor(v, 8);
    return v;
}
__device__ inline float red64sum(float v) {
    v += __shfl_xor(v, 1);
    v += __shfl_xor(v, 2);
    v += __shfl_xor(v, 4);
    v += __shfl_xor(v, 8);
    v += __shfl_xor(v, 16);
    v += __shfl_xor(v, 32);
    return v;
}

// ------ fused fp32->bf16 convert: hs, W1, W2, keys(x0.125) + keys passthrough ------
__global__ __launch_bounds__(256) void k_cvt4(const float* __restrict__ s0, u16* __restrict__ d0,
                                              const float* __restrict__ s1, u16* __restrict__ d1,
                                              const float* __restrict__ s2, u16* __restrict__ d2,
                                              const float* __restrict__ s3, u16* __restrict__ d3,
                                              float* __restrict__ outk) {
    int b = blockIdx.x;
    if (b >= 4096) {  // keys: scale 1/8 into k_b (align term rescaled by 8 in k_attn)
        int i = (b - 4096) * 256 + threadIdx.x;
        f4 v = ((const f4*)s3)[i];
        ((f4*)outk)[i] = v;  // passthrough copy to out
        u16x4 o;
        o[0] = f2bf(v[0] * 0.125f); o[1] = f2bf(v[1] * 0.125f);
        o[2] = f2bf(v[2] * 0.125f); o[3] = f2bf(v[3] * 0.125f);
        ((u16x4*)d3)[i] = o;
        return;
    }
    const float* s; u16* d; int base;
    if (b < 2048)      { s = s0; d = d0; base = 0; }
    else if (b < 3072) { s = s1; d = d1; base = 2048; }
    else               { s = s2; d = d2; base = 3072; }
    int i = (b - base) * 256 + threadIdx.x;
    f4 v = ((const f4*)s)[i];
    u16x4 o;
    o[0] = f2bf(v[0]); o[1] = f2bf(v[1]); o[2] = f2bf(v[2]); o[3] = f2bf(v[3]);
    ((u16x4*)d)[i] = o;
}

// ------ V transpose: [BH,T,64] f32 -> [BH,64,T] bf16, + values passthrough ------
__global__ __launch_bounds__(256) void k_vtrans(const float* __restrict__ V,
                                                u16* __restrict__ Vt,
                                                float* __restrict__ outv) {
    __shared__ float tile[64][65];
    int bh = blockIdx.y, t0 = blockIdx.x * 64;
    int r = threadIdx.x >> 2, c0 = (threadIdx.x & 3) * 16;
    const float* vp = V + ((size_t)bh * TT + t0) * HDD;
#pragma unroll
    for (int j = 0; j < 16; j += 4) {
        f4 v = *(const f4*)(vp + r * HDD + c0 + j);
        tile[r][c0 + j + 0] = v[0]; tile[r][c0 + j + 1] = v[1];
        tile[r][c0 + j + 2] = v[2]; tile[r][c0 + j + 3] = v[3];
        *(f4*)(outv + ((size_t)bh * TT + t0 + r) * HDD + c0 + j) = v;
    }
    __syncthreads();
    int d = threadIdx.x >> 2, x0 = (threadIdx.x & 3) * 16;
    u16* op = Vt + ((size_t)bh * HDD + d) * TT + t0 + x0;
#pragma unroll
    for (int j = 0; j < 16; j += 4) {
        u16x4 o;
        o[0] = f2bf(tile[x0 + j + 0][d]); o[1] = f2bf(tile[x0 + j + 1][d]);
        o[2] = f2bf(tile[x0 + j + 2][d]); o[3] = f2bf(tile[x0 + j + 3][d]);
        *(u16x4*)(op + j) = o;
    }
}

// ---------------- GEMM: C[M,N] = A[M,K] * B[N,K]^T + bias ----------------
// EPI 0: out row-major [M,N] fp32.
// EPI 1: out = A5*que + CC*(acc+bias) scattered to [B,NH,T,HD]  (PCN base).
template <int EPI>
__global__ __launch_bounds__(256) void k_gemm_bt(const u16* __restrict__ A,
                                                 const u16* __restrict__ Bm,
                                                 const float* __restrict__ bias,
                                                 const float* __restrict__ que,
                                                 float* __restrict__ out) {
    const int K = 1024, N = 1024;
    int w = threadIdx.x >> 6, l = threadIdx.x & 63, lr = l & 15, lg = l >> 4;
    int m0 = blockIdx.y * 64 + w * 16;
    int n0 = blockIdx.x * 64;
    const u16* ap = A + (size_t)(m0 + lr) * K + lg * 8;
    const u16* bp = Bm + (size_t)(n0 + lr) * K + lg * 8;
    f4 z4 = {0.f, 0.f, 0.f, 0.f};
    f4 acc[4] = {z4, z4, z4, z4};
#pragma unroll 2
    for (int kk = 0; kk < K; kk += 32) {
        bf16x8 a  = *(const bf16x8*)(ap + kk);
        bf16x8 b0 = *(const bf16x8*)(bp + kk);
        bf16x8 b1 = *(const bf16x8*)(bp + 16 * K + kk);
        bf16x8 b2 = *(const bf16x8*)(bp + 32 * K + kk);
        bf16x8 b3 = *(const bf16x8*)(bp + 48 * K + kk);
        acc[0] = __builtin_amdgcn_mfma_f32_16x16x32_bf16(a, b0, acc[0], 0, 0, 0);
        acc[1] = __builtin_amdgcn_mfma_f32_16x16x32_bf16(a, b1, acc[1], 0, 0, 0);
        acc[2] = __builtin_amdgcn_mfma_f32_16x16x32_bf16(a, b2, acc[2], 0, 0, 0);
        acc[3] = __builtin_amdgcn_mfma_f32_16x16x32_bf16(a, b3, acc[3], 0, 0, 0);
    }
    const float A5 = 0.9509900499f, CC = 1.0f - A5;
#pragma unroll
    for (int cf = 0; cf < 4; ++cf) {
        int col = n0 + cf * 16 + lr;
        float bs = bias[col];
#pragma unroll
        for (int r = 0; r < 4; ++r) {
            int row = m0 + lg * 4 + r;
            float v = acc[cf][r] + bs;
            if (EPI == 0) {
                out[(size_t)row * N + col] = v;
            } else {
                int b = row >> 10, t = row & 1023, nh = col >> 6, hd = col & 63;
                size_t oidx = (((size_t)(b * NHH + nh)) * TT + t) * HDD + hd;
                out[oidx] = A5 * que[oidx] + CC * v;
            }
        }
    }
}

// ---------------- LayerNorm + ReLU -> bf16 ----------------
__global__ __launch_bounds__(256) void k_lnrelu(const float* __restrict__ X,
                                                const float* __restrict__ g,
                                                const float* __restrict__ bta,
                                                u16* __restrict__ xr) {
    int row = blockIdx.x;
    f4 v = ((const f4*)(X + (size_t)row * HH))[threadIdx.x];
    float s = v[0] + v[1] + v[2] + v[3];
    float s2 = v[0] * v[0] + v[1] * v[1] + v[2] * v[2] + v[3] * v[3];
    s = red64sum(s);
    s2 = red64sum(s2);
    __shared__ float red[8];
    int w = threadIdx.x >> 6, l = threadIdx.x & 63;
    if (l == 0) { red[w] = s; red[w + 4] = s2; }
    __syncthreads();
    float S1 = red[0] + red[1] + red[2] + red[3];
    float S2 = red[4] + red[5] + red[6] + red[7];
    float mu = S1 * (1.0f / 1024.0f);
    float var = S2 * (1.0f / 1024.0f) - mu * mu;
    float rstd = rsqrtf(var + 1e-5f);
    f4 gv = ((const f4*)g)[threadIdx.x];
    f4 bv = ((const f4*)bta)[threadIdx.x];
    u16x4 o;
#pragma unroll
    for (int j = 0; j < 4; ++j) {
        float y = (v[j] - mu) * rstd * gv[j] + bv[j];
        y = fmaxf(y, 0.f);
        o[j] = f2bf(y);
    }
    ((u16x4*)(xr + (size_t)row * HH))[threadIdx.x] = o;
}

// ------- fused q-formation + flash attention + energy stats -------
// 128 q-rows/block, 768 blocks (3/CU), XCD-colocated per (b,h) (bi%32).
// q = base + CH*hyp_s + sum_k C_k*rn_{s,k}  (base = A5*que+CC*ctx from GEMM2).
// Non-swapped QK^T, P through per-wave swizzled LDS (R5 path, best measured).
// K/V double-buffered in LDS: ONE barrier per kt. align from QK diagonal.
// Max-free softmax (|s|<~15 bounded; exp fits fp32).
__global__ __launch_bounds__(256, 3) void k_attn(const float* __restrict__ basep_,
                                                 const float* __restrict__ hyp,
                                                 const float* __restrict__ rn,
                                                 const u16* __restrict__ Kb,
                                                 const u16* __restrict__ Vt,
                                                 u16* __restrict__ qq,
                                                 float* __restrict__ part) {
    int bi = blockIdx.x;
    int p_ = bi & 31, j_ = bi >> 5;      // XCD swizzle: same (b,h) -> same XCD
    int h = p_ & 15, b = p_ >> 4;
    int s = j_ >> 3, qt2 = j_ & 7;
    int sb = s * 2 + b;
    int bh = b * NHH + h;
    int pi = sb * 128 + h * 8 + qt2;
    int w = threadIdx.x >> 6, l = threadIdx.x & 63, lr = l & 15, lg = l >> 4;
    int t0 = qt2 * 128;
    f4 z4 = {0.f, 0.f, 0.f, 0.f};

    __shared__ u16 Ks[2][4096];     // 64x64, byte ^= ((row&7)<<4), double-buffered
    __shared__ u16 Vs[2][4096];
    __shared__ u16 plds[8][1024];   // per (wave,qr) 16x64 P tile, swizzled

    // ---- fused q formation in fragment layout ----
    const float CH = 0.1f * 0.9509900499f;
    const float C0 = 0.0096059601f, C1 = 0.0097029900f, C2 = 0.0098010000f, C3 = 0.0099f;
    const float* basep = basep_ + ((size_t)bh * TT) * HDD;
    const float* hypp = hyp + ((size_t)(sb * NHH + h) * TT) * HDD;
    const float* rn0p = rn + ((size_t)(((s * 4 + 0) * 2 + b) * NHH + h) * TT) * HDD;
    const float* rn1p = rn + ((size_t)(((s * 4 + 1) * 2 + b) * NHH + h) * TT) * HDD;
    const float* rn2p = rn + ((size_t)(((s * 4 + 2) * 2 + b) * NHH + h) * TT) * HDD;
    const float* rn3p = rn + ((size_t)(((s * 4 + 3) * 2 + b) * NHH + h) * TT) * HDD;
    u16* qqp = qq + ((size_t)(sb * NHH + h) * TT) * HDD;

    bf16x8 aq[2][2];
#pragma unroll
    for (int qr = 0; qr < 2; ++qr) {
        size_t ro = (size_t)(t0 + w * 32 + qr * 16 + lr) * HDD;
#pragma unroll
        for (int c = 0; c < 2; ++c) {
            int d0 = c * 32 + lg * 8;
            f4 va, vb;
#pragma unroll
            for (int half = 0; half < 2; ++half) {
                size_t off = ro + d0 + half * 4;
                f4 v = *(const f4*)(basep + off);
                v += CH * __builtin_nontemporal_load((const f4*)(hypp + off));
                v += C0 * __builtin_nontemporal_load((const f4*)(rn0p + off));
                v += C1 * __builtin_nontemporal_load((const f4*)(rn1p + off));
                v += C2 * __builtin_nontemporal_load((const f4*)(rn2p + off));
                v += C3 * __builtin_nontemporal_load((const f4*)(rn3p + off));
                if (half == 0) va = v; else vb = v;
            }
            union { bf16x8 f; u16 u[8]; int4 i4; } o;
#pragma unroll
            for (int j = 0; j < 4; ++j) { o.u[j] = f2bf(va[j]); o.u[4 + j] = f2bf(vb[j]); }
            aq[qr][c] = o.f;
            *(int4*)(qqp + ro + d0) = o.i4;   // for k_select
        }
    }

    // staging addresses (thread covers 16B units u and u+256 of each 8KB tile)
    const u16* kbase = Kb + (size_t)bh * TT * HDD;
    const u16* vbase = Vt + (size_t)bh * HDD * TT;
    int u0 = threadIdx.x, u1 = threadIdx.x + 256;
    const u16* kg0 = kbase + u0 * 8;
    const u16* kg1 = kbase + u1 * 8;
    const u16* vg0 = vbase + (size_t)(u0 >> 3) * TT + (u0 & 7) * 8;
    const u16* vg1 = vbase + (size_t)(u1 >> 3) * TT + (u1 & 7) * 8;
    int ko0 = (u0 >> 3) * 128 + (((u0 & 7) ^ ((u0 >> 3) & 7)) << 4);
    int ko1 = (u1 >> 3) * 128 + (((u1 & 7) ^ ((u1 >> 3) & 7)) << 4);

    // prologue: stage tile 0 into buffer 0
    int4 kr0 = *(const int4*)(kg0);
    int4 kr1 = *(const int4*)(kg1);
    int4 vr0 = *(const int4*)(vg0);
    int4 vr1 = *(const int4*)(vg1);
    *(int4*)((char*)Ks[0] + ko0) = kr0;
    *(int4*)((char*)Ks[0] + ko1) = kr1;
    *(int4*)((char*)Vs[0] + ko0) = vr0;
    *(int4*)((char*)Vs[0] + ko1) = vr1;
    __syncthreads();

    f4 acco[2][4] = {{z4, z4, z4, z4}, {z4, z4, z4, z4}};
    float zrow[2][4] = {{0.f, 0.f, 0.f, 0.f}, {0.f, 0.f, 0.f, 0.f}};
    float wrow[2][4] = {{0.f, 0.f, 0.f, 0.f}, {0.f, 0.f, 0.f, 0.f}};
    float al_lane = 0.f;
    int kdiag = qt2 * 2 + (w >> 1);   // kt holding this wave's diagonal elements

    for (int kt = 0; kt < 16; ++kt) {
        int cur = kt & 1;
        if (kt < 15) {  // issue next-tile loads; latency hides under compute
            kr0 = *(const int4*)(kg0 + (kt + 1) * 4096);
            kr1 = *(const int4*)(kg1 + (kt + 1) * 4096);
            vr0 = *(const int4*)(vg0 + (kt + 1) * 64);
            vr1 = *(const int4*)(vg1 + (kt + 1) * 64);
        }
        char* KsB = (char*)Ks[cur];
        char* VsB = (char*)Vs[cur];

        // QK^T: K frags shared across both row-frags
        f4 sc[2][4];
#pragma unroll
        for (int cf = 0; cf < 4; ++cf) {
            int row = cf * 16 + lr, rs = row & 7;
            bf16x8 bk0 = *(const bf16x8*)(KsB + row * 128 + ((lg ^ rs) << 4));
            bf16x8 bk1 = *(const bf16x8*)(KsB + row * 128 + (((4 + lg) ^ rs) << 4));
            f4 t0a = __builtin_amdgcn_mfma_f32_16x16x32_bf16(aq[0][0], bk0, z4, 0, 0, 0);
            sc[0][cf] = __builtin_amdgcn_mfma_f32_16x16x32_bf16(aq[0][1], bk1, t0a, 0, 0, 0);
            f4 t1a = __builtin_amdgcn_mfma_f32_16x16x32_bf16(aq[1][0], bk0, z4, 0, 0, 0);
            sc[1][cf] = __builtin_amdgcn_mfma_f32_16x16x32_bf16(aq[1][1], bk1, t1a, 0, 0, 0);
        }

        // align from diagonal: row L = w*32+qr*16+lg*4+r meets col k at
        // kt==kdiag, cf=(2w+qr)&3, on lanes lr==lg*4+r. S has 1/8 scale -> x8.
        if (kt == kdiag) {
            f4 sd0 = (w & 1) ? sc[0][2] : sc[0][0];
            f4 sd1 = (w & 1) ? sc[1][3] : sc[1][1];
            int rr = lr & 3;
            float e0 = rr == 0 ? sd0[0] : (rr == 1 ? sd0[1] : (rr == 2 ? sd0[2] : sd0[3]));
            float e1 = rr == 0 ? sd1[0] : (rr == 1 ? sd1[1] : (rr == 2 ? sd1[2] : sd1[3]));
            if (lg == (lr >> 2)) al_lane += (e0 + e1) * 8.0f;
        }

        // softmax partials (m=0) + P -> per-wave LDS bf16
#pragma unroll
        for (int qr = 0; qr < 2; ++qr) {
            u16* pl = &plds[w * 2 + qr][0];
#pragma unroll
            for (int cf = 0; cf < 4; ++cf) {
#pragma unroll
                for (int r = 0; r < 4; ++r) {
                    float sv = sc[qr][cf][r];
                    float pe = __expf(sv);
                    zrow[qr][r] += pe;
                    wrow[qr][r] = fmaf(pe, sv, wrow[qr][r]);
                    int prow = lg * 4 + r;
                    pl[(prow * 64 + cf * 16 + lr) ^ ((prow & 7) << 3)] = f2bf(pe);
                }
            }
        }
        bf16x8 pa[2][2];
#pragma unroll
        for (int qr = 0; qr < 2; ++qr) {
            const u16* pl = &plds[w * 2 + qr][0];
            pa[qr][0] = *(const bf16x8*)&pl[(lr * 64 + lg * 8) ^ ((lr & 7) << 3)];
            pa[qr][1] = *(const bf16x8*)&pl[(lr * 64 + 32 + lg * 8) ^ ((lr & 7) << 3)];
        }
        // PV: V frags shared across both row-frags
#pragma unroll
        for (int cf = 0; cf < 4; ++cf) {
            int row = cf * 16 + lr, rs = row & 7;
            bf16x8 bv0 = *(const bf16x8*)(VsB + row * 128 + ((lg ^ rs) << 4));
            bf16x8 bv1 = *(const bf16x8*)(VsB + row * 128 + (((4 + lg) ^ rs) << 4));
            acco[0][cf] = __builtin_amdgcn_mfma_f32_16x16x32_bf16(pa[0][0], bv0, acco[0][cf], 0, 0, 0);
            acco[0][cf] = __builtin_amdgcn_mfma_f32_16x16x32_bf16(pa[0][1], bv1, acco[0][cf], 0, 0, 0);
            acco[1][cf] = __builtin_amdgcn_mfma_f32_16x16x32_bf16(pa[1][0], bv0, acco[1][cf], 0, 0, 0);
            acco[1][cf] = __builtin_amdgcn_mfma_f32_16x16x32_bf16(pa[1][1], bv1, acco[1][cf], 0, 0, 0);
        }

        if (kt < 15) {  // write tile kt+1 into the idle buffer
            char* Kn = (char*)Ks[cur ^ 1];
            char* Vn = (char*)Vs[cur ^ 1];
            *(int4*)(Kn + ko0) = kr0;
            *(int4*)(Kn + ko1) = kr1;
            *(int4*)(Vn + ko0) = vr0;
            *(int4*)(Vn + ko1) = vr1;
        }
        __syncthreads();   // single barrier per kt
    }

    // per-row finalize: out_mag & entropy (m = 0)
    float magw = 0.f, entw = 0.f;
#pragma unroll
    for (int qr = 0; qr < 2; ++qr) {
#pragma unroll
        for (int r = 0; r < 4; ++r) {
            float zz = red16sum(zrow[qr][r]);
            float ww = red16sum(wrow[qr][r]);
            float ssq = acco[qr][0][r] * acco[qr][0][r] + acco[qr][1][r] * acco[qr][1][r] +
                        acco[qr][2][r] * acco[qr][2][r] + acco[qr][3][r] * acco[qr][3][r];
            ssq = red16sum(ssq);
            float inv = 1.0f / zz;
            magw += sqrtf(ssq) * inv;
            entw += __logf(zz) - ww * inv;
        }
    }
    magw += __shfl_xor(magw, 16); magw += __shfl_xor(magw, 32);
    entw += __shfl_xor(entw, 16); entw += __shfl_xor(entw, 32);
    float al = red64sum(al_lane);

    __shared__ float red[4][3];
    if (l == 0) { red[w][0] = magw; red[w][1] = entw; red[w][2] = al; }
    __syncthreads();
    if (threadIdx.x == 0) {
        part[pi * 3 + 0] = red[0][0] + red[1][0] + red[2][0] + red[3][0];
        part[pi * 3 + 1] = red[0][1] + red[1][1] + red[2][1] + red[3][1];
        part[pi * 3 + 2] = red[0][2] + red[1][2] + red[2][2] + red[3][2];
    }
}

// ---------------- energy reduce + softmax over samples ----------------
__global__ void k_finalize(const float* __restrict__ part, float* __restrict__ probs) {
    int w = threadIdx.x >> 6, l = threadIdx.x & 63;
    __shared__ float eng[6];
    if (w < 6) {
        float a0 = 0.f, a1 = 0.f, a2 = 0.f;
        for (int i = l; i < 128; i += 64) {
            const float* pp = part + (size_t)(w * 128 + i) * 3;
            a0 += pp[0]; a1 += pp[1]; a2 += pp[2];
        }
        a0 = red64sum(a0); a1 = red64sum(a1); a2 = red64sum(a2);
        if (l == 0) {
            const float inv = 1.0f / 16384.0f;
            eng[w] = a0 * inv - 0.1f * (a1 * inv) - 0.05f * (a2 * inv);
        }
    }
    __syncthreads();
    if (threadIdx.x < 2) {
        int b = threadIdx.x;
        float e0 = -eng[0 + b], e1 = -eng[2 + b], e2 = -eng[4 + b];
        float mx = fmaxf(e0, fmaxf(e1, e2));
        float x0 = __expf(e0 - mx), x1 = __expf(e1 - mx), x2 = __expf(e2 - mx);
        float inv = 1.0f / (x0 + x1 + x2);
        probs[0 + b] = x0 * inv;
        probs[2 + b] = x1 * inv;
        probs[4 + b] = x2 * inv;
    }
}

// ---------------- selected = sum_s probs[s,b]*q[s] (q in bf16) ----------------
__global__ __launch_bounds__(256) void k_select(const u16* __restrict__ qq,
                                                const float* __restrict__ probs,
                                                float* __restrict__ out) {
    const int NQ4 = 524288;               // u16x4 groups per sample
    int i = blockIdx.x * 256 + threadIdx.x;
    int b = i >> 18;                      // 262144 groups per batch
    float p0 = probs[0 + b], p1 = probs[2 + b], p2 = probs[4 + b];
    u16x4 a0 = ((const u16x4*)qq)[i];
    u16x4 a1 = ((const u16x4*)qq)[NQ4 + i];
    u16x4 a2 = ((const u16x4*)qq)[2 * NQ4 + i];
    f4 v;
#pragma unroll
    for (int j = 0; j < 4; ++j)
        v[j] = p0 * bf2f(a0[j]) + p1 * bf2f(a1[j]) + p2 * bf2f(a2[j]);
    ((f4*)out)[i] = v;
}

extern "C" void kernel_launch(void* const* d_in, const int* in_sizes, int n_in,
                              void* d_out, int out_size, void* d_ws, size_t ws_size,
                              hipStream_t stream) {
    const float* queries = (const float*)d_in[0];
    const float* keys    = (const float*)d_in[1];
    const float* values  = (const float*)d_in[2];
    const float* hs      = (const float*)d_in[3];
    const float* W1      = (const float*)d_in[4];
    const float* b1      = (const float*)d_in[5];
    const float* ln_g    = (const float*)d_in[6];
    const float* ln_b    = (const float*)d_in[7];
    const float* W2      = (const float*)d_in[8];
    const float* b2      = (const float*)d_in[9];
    const float* hyp     = (const float*)d_in[10];
    const float* rn      = (const float*)d_in[11];
    float* out = (float*)d_out;
    char* ws = (char*)d_ws;

    const size_t MB = 1024ull * 1024ull;
    // qq16 occupies [0,12MB); MLP temporaries overlap it (all dead before k_attn)
    u16*   qq16 = (u16*)(ws);                   // 12 MB  [S,B,NH,T,HD] bf16
    u16*   hs_b = (u16*)(ws + 0 * MB);          //  4 MB  (dead after gemm1)
    u16*   w1_b = (u16*)(ws + 4 * MB);          //  2 MB  (dead after gemm1)
    u16*   w2_b = (u16*)(ws + 6 * MB);          //  2 MB  (dead after gemm2)
    float* X    = (float*)(ws + 8 * MB);        //  8 MB  (dead after lnrelu)
    u16*   xr   = (u16*)(ws + 16 * MB);         //  4 MB  (dead after gemm2)
    float* base = (float*)(ws + 24 * MB);       //  8 MB  (A5*que + CC*ctx)
    u16*   k_b  = (u16*)(ws + 32 * MB);         //  4 MB  (keys * 0.125, bf16)
    u16*   vt_b = (u16*)(ws + 36 * MB);         //  4 MB
    float* part = (float*)(ws + 40 * MB);       //  9 KB
    float* probs= (float*)(ws + 40 * MB + 65536);

    k_cvt4<<<6144, 256, 0, stream>>>(hs, hs_b, W1, w1_b, W2, w2_b, keys, k_b,
                                     out + 2097152);
    k_vtrans<<<dim3(16, 32), 256, 0, stream>>>(values, vt_b, out + 4194304);

    k_gemm_bt<0><<<dim3(16, 32), 256, 0, stream>>>(hs_b, w1_b, b1, nullptr, X);
    k_lnrelu<<<2048, 256, 0, stream>>>(X, ln_g, ln_b, xr);
    k_gemm_bt<1><<<dim3(16, 32), 256, 0, stream>>>(xr, w2_b, b2, queries, base);

    k_attn<<<768, 256, 0, stream>>>(base, hyp, rn, k_b, vt_b, qq16, part);
    k_finalize<<<1, 384, 0, stream>>>(part, probs);
    k_select<<<2048, 256, 0, stream>>>(qq16, probs, out);
}

// Round 9
// 170.243 us; speedup vs baseline: 1.1348x; 1.0133x over previous
//
#include <hip/hip_runtime.h>
#include <hip/hip_bf16.h>
#include <math.h>

#define NB 2
#define NHH 16
#define TT 1024
#define HDD 64
#define NSS 3
#define HH 1024
#define MMR 2048  // NB*TT

typedef float f4 __attribute__((ext_vector_type(4)));
typedef short bf16x8 __attribute__((ext_vector_type(8)));
typedef unsigned short u16;
typedef u16 u16x4 __attribute__((ext_vector_type(4)));

__device__ inline u16 f2bf(float f) {
    union { float f; unsigned u; } v; v.f = f;
    unsigned r = (v.u + 0x7FFFu + ((v.u >> 16) & 1u)) >> 16;
    return (u16)r;
}
__device__ inline float bf2f(u16 u) {
    union { unsigned u; float f; } v; v.u = ((unsigned)u) << 16;
    return v.f;
}

__device__ inline float red16sum(float v) {
    v += __shfl_xor(v, 1);
    v += __shfl_xor(v, 2);
    v += __shfl_xor(v, 4);
    v += __shfl_xor(v, 8);
    return v;
}
__device__ inline float red64sum(float v) {
    v += __shfl_xor(v, 1);
    v += __shfl_xor(v, 2);
    v += __shfl_xor(v, 4);
    v += __shfl_xor(v, 8);
    v += __shfl_xor(v, 16);
    v += __shfl_xor(v, 32);
    return v;
}

// ------ fused fp32->bf16 convert: hs, W1, W2, keys(x0.125) + keys passthrough ------
__global__ __launch_bounds__(256) void k_cvt4(const float* __restrict__ s0, u16* __restrict__ d0,
                                              const float* __restrict__ s1, u16* __restrict__ d1,
                                              const float* __restrict__ s2, u16* __restrict__ d2,
                                              const float* __restrict__ s3, u16* __restrict__ d3,
                                              float* __restrict__ outk) {
    int b = blockIdx.x;
    if (b >= 4096) {  // keys: scale 1/8 into k_b (align term rescaled by 8 in k_attn)
        int i = (b - 4096) * 256 + threadIdx.x;
        f4 v = ((const f4*)s3)[i];
        ((f4*)outk)[i] = v;  // passthrough copy to out
        u16x4 o;
        o[0] = f2bf(v[0] * 0.125f); o[1] = f2bf(v[1] * 0.125f);
        o[2] = f2bf(v[2] * 0.125f); o[3] = f2bf(v[3] * 0.125f);
        ((u16x4*)d3)[i] = o;
        return;
    }
    const float* s; u16* d; int base;
    if (b < 2048)      { s = s0; d = d0; base = 0; }
    else if (b < 3072) { s = s1; d = d1; base = 2048; }
    else               { s = s2; d = d2; base = 3072; }
    int i = (b - base) * 256 + threadIdx.x;
    f4 v = ((const f4*)s)[i];
    u16x4 o;
    o[0] = f2bf(v[0]); o[1] = f2bf(v[1]); o[2] = f2bf(v[2]); o[3] = f2bf(v[3]);
    ((u16x4*)d)[i] = o;
}

// ------ V transpose: [BH,T,64] f32 -> [BH,64,T] bf16, + values passthrough ------
__global__ __launch_bounds__(256) void k_vtrans(const float* __restrict__ V,
                                                u16* __restrict__ Vt,
                                                float* __restrict__ outv) {
    __shared__ float tile[64][65];
    int bh = blockIdx.y, t0 = blockIdx.x * 64;
    int r = threadIdx.x >> 2, c0 = (threadIdx.x & 3) * 16;
    const float* vp = V + ((size_t)bh * TT + t0) * HDD;
#pragma unroll
    for (int j = 0; j < 16; j += 4) {
        f4 v = *(const f4*)(vp + r * HDD + c0 + j);
        tile[r][c0 + j + 0] = v[0]; tile[r][c0 + j + 1] = v[1];
        tile[r][c0 + j + 2] = v[2]; tile[r][c0 + j + 3] = v[3];
        *(f4*)(outv + ((size_t)bh * TT + t0 + r) * HDD + c0 + j) = v;
    }
    __syncthreads();
    int d = threadIdx.x >> 2, x0 = (threadIdx.x & 3) * 16;
    u16* op = Vt + ((size_t)bh * HDD + d) * TT + t0 + x0;
#pragma unroll
    for (int j = 0; j < 16; j += 4) {
        u16x4 o;
        o[0] = f2bf(tile[x0 + j + 0][d]); o[1] = f2bf(tile[x0 + j + 1][d]);
        o[2] = f2bf(tile[x0 + j + 2][d]); o[3] = f2bf(tile[x0 + j + 3][d]);
        *(u16x4*)(op + j) = o;
    }
}

// ---------------- GEMM: C[M,N] = A[M,K] * B[N,K]^T + bias ----------------
// EPI 0: out row-major [M,N] fp32.
// EPI 1: out = A5*que + CC*(acc+bias) scattered to [B,NH,T,HD]  (PCN base).
template <int EPI>
__global__ __launch_bounds__(256) void k_gemm_bt(const u16* __restrict__ A,
                                                 const u16* __restrict__ Bm,
                                                 const float* __restrict__ bias,
                                                 const float* __restrict__ que,
                                                 float* __restrict__ out) {
    const int K = 1024, N = 1024;
    int w = threadIdx.x >> 6, l = threadIdx.x & 63, lr = l & 15, lg = l >> 4;
    int m0 = blockIdx.y * 64 + w * 16;
    int n0 = blockIdx.x * 64;
    const u16* ap = A + (size_t)(m0 + lr) * K + lg * 8;
    const u16* bp = Bm + (size_t)(n0 + lr) * K + lg * 8;
    f4 z4 = {0.f, 0.f, 0.f, 0.f};
    f4 acc[4] = {z4, z4, z4, z4};
#pragma unroll 2
    for (int kk = 0; kk < K; kk += 32) {
        bf16x8 a  = *(const bf16x8*)(ap + kk);
        bf16x8 b0 = *(const bf16x8*)(bp + kk);
        bf16x8 b1 = *(const bf16x8*)(bp + 16 * K + kk);
        bf16x8 b2 = *(const bf16x8*)(bp + 32 * K + kk);
        bf16x8 b3 = *(const bf16x8*)(bp + 48 * K + kk);
        acc[0] = __builtin_amdgcn_mfma_f32_16x16x32_bf16(a, b0, acc[0], 0, 0, 0);
        acc[1] = __builtin_amdgcn_mfma_f32_16x16x32_bf16(a, b1, acc[1], 0, 0, 0);
        acc[2] = __builtin_amdgcn_mfma_f32_16x16x32_bf16(a, b2, acc[2], 0, 0, 0);
        acc[3] = __builtin_amdgcn_mfma_f32_16x16x32_bf16(a, b3, acc[3], 0, 0, 0);
    }
    const float A5 = 0.9509900499f, CC = 1.0f - A5;
#pragma unroll
    for (int cf = 0; cf < 4; ++cf) {
        int col = n0 + cf * 16 + lr;
        float bs = bias[col];
#pragma unroll
        for (int r = 0; r < 4; ++r) {
            int row = m0 + lg * 4 + r;
            float v = acc[cf][r] + bs;
            if (EPI == 0) {
                out[(size_t)row * N + col] = v;
            } else {
                int b = row >> 10, t = row & 1023, nh = col >> 6, hd = col & 63;
                size_t oidx = (((size_t)(b * NHH + nh)) * TT + t) * HDD + hd;
                out[oidx] = A5 * que[oidx] + CC * v;
            }
        }
    }
}

// ---------------- LayerNorm + ReLU -> bf16 ----------------
__global__ __launch_bounds__(256) void k_lnrelu(const float* __restrict__ X,
                                                const float* __restrict__ g,
                                                const float* __restrict__ bta,
                                                u16* __restrict__ xr) {
    int row = blockIdx.x;
    f4 v = ((const f4*)(X + (size_t)row * HH))[threadIdx.x];
    float s = v[0] + v[1] + v[2] + v[3];
    float s2 = v[0] * v[0] + v[1] * v[1] + v[2] * v[2] + v[3] * v[3];
    s = red64sum(s);
    s2 = red64sum(s2);
    __shared__ float red[8];
    int w = threadIdx.x >> 6, l = threadIdx.x & 63;
    if (l == 0) { red[w] = s; red[w + 4] = s2; }
    __syncthreads();
    float S1 = red[0] + red[1] + red[2] + red[3];
    float S2 = red[4] + red[5] + red[6] + red[7];
    float mu = S1 * (1.0f / 1024.0f);
    float var = S2 * (1.0f / 1024.0f) - mu * mu;
    float rstd = rsqrtf(var + 1e-5f);
    f4 gv = ((const f4*)g)[threadIdx.x];
    f4 bv = ((const f4*)bta)[threadIdx.x];
    u16x4 o;
#pragma unroll
    for (int j = 0; j < 4; ++j) {
        float y = (v[j] - mu) * rstd * gv[j] + bv[j];
        y = fmaxf(y, 0.f);
        o[j] = f2bf(y);
    }
    ((u16x4*)(xr + (size_t)row * HH))[threadIdx.x] = o;
}

// ------- fused q-formation + flash attention + energy stats -------
// 128 q-rows/block, 768 blocks (3/CU), XCD-colocated per (b,h) (bi%32).
// q-formation is COALESCED: threads linearly load the 6 streams, combine,
// pack bf16, write the 128x64 q-slab into swizzled LDS (reusing plds space)
// and qq to global. Frags then read from LDS (conflict-free). Single-barrier
// double-buffered K/V loop; align from QK diagonal; max-free softmax.
__global__ __launch_bounds__(256, 3) void k_attn(const float* __restrict__ basep_,
                                                 const float* __restrict__ hyp,
                                                 const float* __restrict__ rn,
                                                 const u16* __restrict__ Kb,
                                                 const u16* __restrict__ Vt,
                                                 u16* __restrict__ qq,
                                                 float* __restrict__ part) {
    int bi = blockIdx.x;
    int p_ = bi & 31, j_ = bi >> 5;      // XCD swizzle: same (b,h) -> same XCD
    int h = p_ & 15, b = p_ >> 4;
    int s = j_ >> 3, qt2 = j_ & 7;
    int sb = s * 2 + b;
    int bh = b * NHH + h;
    int pi = sb * 128 + h * 8 + qt2;
    int w = threadIdx.x >> 6, l = threadIdx.x & 63, lr = l & 15, lg = l >> 4;
    int t0 = qt2 * 128;
    f4 z4 = {0.f, 0.f, 0.f, 0.f};

    __shared__ u16 Ks[2][4096];     // 64x64, byte ^= ((row&7)<<4), double-buffered
    __shared__ u16 Vs[2][4096];
    __shared__ u16 plds[8][1024];   // q-slab (prologue) then per-wave P tiles

    const float CH = 0.1f * 0.9509900499f;
    const float C0 = 0.0096059601f, C1 = 0.0097029900f, C2 = 0.0098010000f, C3 = 0.0099f;
    const float* basep = basep_ + ((size_t)bh * TT) * HDD;
    const float* hypp = hyp + ((size_t)(sb * NHH + h) * TT) * HDD;
    const float* rn0p = rn + ((size_t)(((s * 4 + 0) * 2 + b) * NHH + h) * TT) * HDD;
    const float* rn1p = rn + ((size_t)(((s * 4 + 1) * 2 + b) * NHH + h) * TT) * HDD;
    const float* rn2p = rn + ((size_t)(((s * 4 + 2) * 2 + b) * NHH + h) * TT) * HDD;
    const float* rn3p = rn + ((size_t)(((s * 4 + 3) * 2 + b) * NHH + h) * TT) * HDD;
    u16* qqp = qq + ((size_t)(sb * NHH + h) * TT) * HDD;

    // staging addresses for K/V (thread covers 16B units u and u+256 per 8KB tile)
    const u16* kbase = Kb + (size_t)bh * TT * HDD;
    const u16* vbase = Vt + (size_t)bh * HDD * TT;
    int u0 = threadIdx.x, u1 = threadIdx.x + 256;
    const u16* kg0 = kbase + u0 * 8;
    const u16* kg1 = kbase + u1 * 8;
    const u16* vg0 = vbase + (size_t)(u0 >> 3) * TT + (u0 & 7) * 8;
    const u16* vg1 = vbase + (size_t)(u1 >> 3) * TT + (u1 & 7) * 8;
    int ko0 = (u0 >> 3) * 128 + (((u0 & 7) ^ ((u0 >> 3) & 7)) << 4);
    int ko1 = (u1 >> 3) * 128 + (((u1 & 7) ^ ((u1 >> 3) & 7)) << 4);

    // issue K/V tile-0 loads first (in flight during q formation)
    int4 kr0 = *(const int4*)(kg0);
    int4 kr1 = *(const int4*)(kg1);
    int4 vr0 = *(const int4*)(vg0);
    int4 vr1 = *(const int4*)(vg1);

    // ---- coalesced q formation -> LDS slab + qq global ----
    char* slab = (char*)&plds[0][0];
    {
        int t = threadIdx.x;
#pragma unroll
        for (int m = 0; m < 4; ++m) {
            int j = t + 256 * m;                     // 16B bf16 chunk id in [0,1024)
            size_t off = (size_t)t0 * HDD + (size_t)j * 8;
            f4 a0 = *(const f4*)(basep + off);
            f4 a1 = *(const f4*)(basep + off + 4);
            a0 += CH * __builtin_nontemporal_load((const f4*)(hypp + off));
            a1 += CH * __builtin_nontemporal_load((const f4*)(hypp + off + 4));
            a0 += C0 * __builtin_nontemporal_load((const f4*)(rn0p + off));
            a1 += C0 * __builtin_nontemporal_load((const f4*)(rn0p + off + 4));
            a0 += C1 * __builtin_nontemporal_load((const f4*)(rn1p + off));
            a1 += C1 * __builtin_nontemporal_load((const f4*)(rn1p + off + 4));
            a0 += C2 * __builtin_nontemporal_load((const f4*)(rn2p + off));
            a1 += C2 * __builtin_nontemporal_load((const f4*)(rn2p + off + 4));
            a0 += C3 * __builtin_nontemporal_load((const f4*)(rn3p + off));
            a1 += C3 * __builtin_nontemporal_load((const f4*)(rn3p + off + 4));
            union { u16 u[8]; int4 i4; } o;
#pragma unroll
            for (int k = 0; k < 4; ++k) { o.u[k] = f2bf(a0[k]); o.u[4 + k] = f2bf(a1[k]); }
            int row = j >> 3, slot = j & 7;
            *(int4*)(slab + row * 128 + (((slot ^ (row & 7))) << 4)) = o.i4;
            *(int4*)(qqp + (size_t)t0 * HDD + (size_t)j * 8) = o.i4;  // coalesced
        }
    }
    // stage K/V tile 0
    *(int4*)((char*)Ks[0] + ko0) = kr0;
    *(int4*)((char*)Ks[0] + ko1) = kr1;
    *(int4*)((char*)Vs[0] + ko0) = vr0;
    *(int4*)((char*)Vs[0] + ko1) = vr1;
    __syncthreads();

    // frag reads: each wave reads only its own slab quarter (rows w*32..+31)
    bf16x8 aq[2][2];
#pragma unroll
    for (int qr = 0; qr < 2; ++qr) {
        int r_ = w * 32 + qr * 16 + lr;
#pragma unroll
        for (int c = 0; c < 2; ++c)
            aq[qr][c] = *(const bf16x8*)(slab + r_ * 128 + (((c * 4 + lg) ^ (r_ & 7)) << 4));
    }

    f4 acco[2][4] = {{z4, z4, z4, z4}, {z4, z4, z4, z4}};
    float zrow[2][4] = {{0.f, 0.f, 0.f, 0.f}, {0.f, 0.f, 0.f, 0.f}};
    float wrow[2][4] = {{0.f, 0.f, 0.f, 0.f}, {0.f, 0.f, 0.f, 0.f}};
    float al_lane = 0.f;
    int kdiag = qt2 * 2 + (w >> 1);   // kt holding this wave's diagonal elements

    for (int kt = 0; kt < 16; ++kt) {
        int cur = kt & 1;
        if (kt < 15) {  // issue next-tile loads; latency hides under compute
            kr0 = *(const int4*)(kg0 + (kt + 1) * 4096);
            kr1 = *(const int4*)(kg1 + (kt + 1) * 4096);
            vr0 = *(const int4*)(vg0 + (kt + 1) * 64);
            vr1 = *(const int4*)(vg1 + (kt + 1) * 64);
        }
        char* KsB = (char*)Ks[cur];
        char* VsB = (char*)Vs[cur];

        // QK^T: K frags shared across both row-frags
        f4 sc[2][4];
#pragma unroll
        for (int cf = 0; cf < 4; ++cf) {
            int row = cf * 16 + lr, rs = row & 7;
            bf16x8 bk0 = *(const bf16x8*)(KsB + row * 128 + ((lg ^ rs) << 4));
            bf16x8 bk1 = *(const bf16x8*)(KsB + row * 128 + (((4 + lg) ^ rs) << 4));
            f4 t0a = __builtin_amdgcn_mfma_f32_16x16x32_bf16(aq[0][0], bk0, z4, 0, 0, 0);
            sc[0][cf] = __builtin_amdgcn_mfma_f32_16x16x32_bf16(aq[0][1], bk1, t0a, 0, 0, 0);
            f4 t1a = __builtin_amdgcn_mfma_f32_16x16x32_bf16(aq[1][0], bk0, z4, 0, 0, 0);
            sc[1][cf] = __builtin_amdgcn_mfma_f32_16x16x32_bf16(aq[1][1], bk1, t1a, 0, 0, 0);
        }

        // align from diagonal: row L = w*32+qr*16+lg*4+r meets col k at
        // kt==kdiag, cf=(2w+qr)&3, on lanes lr==lg*4+r. S has 1/8 scale -> x8.
        if (kt == kdiag) {
            f4 sd0 = (w & 1) ? sc[0][2] : sc[0][0];
            f4 sd1 = (w & 1) ? sc[1][3] : sc[1][1];
            int rr = lr & 3;
            float e0 = rr == 0 ? sd0[0] : (rr == 1 ? sd0[1] : (rr == 2 ? sd0[2] : sd0[3]));
            float e1 = rr == 0 ? sd1[0] : (rr == 1 ? sd1[1] : (rr == 2 ? sd1[2] : sd1[3]));
            if (lg == (lr >> 2)) al_lane += (e0 + e1) * 8.0f;
        }

        // softmax partials (m=0) + P -> per-wave LDS bf16
#pragma unroll
        for (int qr = 0; qr < 2; ++qr) {
            u16* pl = &plds[w * 2 + qr][0];
#pragma unroll
            for (int cf = 0; cf < 4; ++cf) {
#pragma unroll
                for (int r = 0; r < 4; ++r) {
                    float sv = sc[qr][cf][r];
                    float pe = __expf(sv);
                    zrow[qr][r] += pe;
                    wrow[qr][r] = fmaf(pe, sv, wrow[qr][r]);
                    int prow = lg * 4 + r;
                    pl[(prow * 64 + cf * 16 + lr) ^ ((prow & 7) << 3)] = f2bf(pe);
                }
            }
        }
        bf16x8 pa[2][2];
#pragma unroll
        for (int qr = 0; qr < 2; ++qr) {
            const u16* pl = &plds[w * 2 + qr][0];
            pa[qr][0] = *(const bf16x8*)&pl[(lr * 64 + lg * 8) ^ ((lr & 7) << 3)];
            pa[qr][1] = *(const bf16x8*)&pl[(lr * 64 + 32 + lg * 8) ^ ((lr & 7) << 3)];
        }
        // PV: V frags shared across both row-frags
#pragma unroll
        for (int cf = 0; cf < 4; ++cf) {
            int row = cf * 16 + lr, rs = row & 7;
            bf16x8 bv0 = *(const bf16x8*)(VsB + row * 128 + ((lg ^ rs) << 4));
            bf16x8 bv1 = *(const bf16x8*)(VsB + row * 128 + (((4 + lg) ^ rs) << 4));
            acco[0][cf] = __builtin_amdgcn_mfma_f32_16x16x32_bf16(pa[0][0], bv0, acco[0][cf], 0, 0, 0);
            acco[0][cf] = __builtin_amdgcn_mfma_f32_16x16x32_bf16(pa[0][1], bv1, acco[0][cf], 0, 0, 0);
            acco[1][cf] = __builtin_amdgcn_mfma_f32_16x16x32_bf16(pa[1][0], bv0, acco[1][cf], 0, 0, 0);
            acco[1][cf] = __builtin_amdgcn_mfma_f32_16x16x32_bf16(pa[1][1], bv1, acco[1][cf], 0, 0, 0);
        }

        if (kt < 15) {  // write tile kt+1 into the idle buffer
            char* Kn = (char*)Ks[cur ^ 1];
            char* Vn = (char*)Vs[cur ^ 1];
            *(int4*)(Kn + ko0) = kr0;
            *(int4*)(Kn + ko1) = kr1;
            *(int4*)(Vn + ko0) = vr0;
            *(int4*)(Vn + ko1) = vr1;
        }
        __syncthreads();   // single barrier per kt
    }

    // per-row finalize: out_mag & entropy (m = 0)
    float magw = 0.f, entw = 0.f;
#pragma unroll
    for (int qr = 0; qr < 2; ++qr) {
#pragma unroll
        for (int r = 0; r < 4; ++r) {
            float zz = red16sum(zrow[qr][r]);
            float ww = red16sum(wrow[qr][r]);
            float ssq = acco[qr][0][r] * acco[qr][0][r] + acco[qr][1][r] * acco[qr][1][r] +
                        acco[qr][2][r] * acco[qr][2][r] + acco[qr][3][r] * acco[qr][3][r];
            ssq = red16sum(ssq);
            float inv = 1.0f / zz;
            magw += sqrtf(ssq) * inv;
            entw += __logf(zz) - ww * inv;
        }
    }
    magw += __shfl_xor(magw, 16); magw += __shfl_xor(magw, 32);
    entw += __shfl_xor(entw, 16); entw += __shfl_xor(entw, 32);
    float al = red64sum(al_lane);

    __shared__ float red[4][3];
    if (l == 0) { red[w][0] = magw; red[w][1] = entw; red[w][2] = al; }
    __syncthreads();
    if (threadIdx.x == 0) {
        part[pi * 3 + 0] = red[0][0] + red[1][0] + red[2][0] + red[3][0];
        part[pi * 3 + 1] = red[0][1] + red[1][1] + red[2][1] + red[3][1];
        part[pi * 3 + 2] = red[0][2] + red[1][2] + red[2][2] + red[3][2];
    }
}

// ---------------- energy reduce + softmax over samples ----------------
__global__ void k_finalize(const float* __restrict__ part, float* __restrict__ probs) {
    int w = threadIdx.x >> 6, l = threadIdx.x & 63;
    __shared__ float eng[6];
    if (w < 6) {
        float a0 = 0.f, a1 = 0.f, a2 = 0.f;
        for (int i = l; i < 128; i += 64) {
            const float* pp = part + (size_t)(w * 128 + i) * 3;
            a0 += pp[0]; a1 += pp[1]; a2 += pp[2];
        }
        a0 = red64sum(a0); a1 = red64sum(a1); a2 = red64sum(a2);
        if (l == 0) {
            const float inv = 1.0f / 16384.0f;
            eng[w] = a0 * inv - 0.1f * (a1 * inv) - 0.05f * (a2 * inv);
        }
    }
    __syncthreads();
    if (threadIdx.x < 2) {
        int b = threadIdx.x;
        float e0 = -eng[0 + b], e1 = -eng[2 + b], e2 = -eng[4 + b];
        float mx = fmaxf(e0, fmaxf(e1, e2));
        float x0 = __expf(e0 - mx), x1 = __expf(e1 - mx), x2 = __expf(e2 - mx);
        float inv = 1.0f / (x0 + x1 + x2);
        probs[0 + b] = x0 * inv;
        probs[2 + b] = x1 * inv;
        probs[4 + b] = x2 * inv;
    }
}

// ---------------- selected = sum_s probs[s,b]*q[s] (q in bf16) ----------------
__global__ __launch_bounds__(256) void k_select(const u16* __restrict__ qq,
                                                const float* __restrict__ probs,
                                                float* __restrict__ out) {
    const int NQ4 = 524288;               // u16x4 groups per sample
    int i = blockIdx.x * 256 + threadIdx.x;
    int b = i >> 18;                      // 262144 groups per batch
    float p0 = probs[0 + b], p1 = probs[2 + b], p2 = probs[4 + b];
    u16x4 a0 = ((const u16x4*)qq)[i];
    u16x4 a1 = ((const u16x4*)qq)[NQ4 + i];
    u16x4 a2 = ((const u16x4*)qq)[2 * NQ4 + i];
    f4 v;
#pragma unroll
    for (int j = 0; j < 4; ++j)
        v[j] = p0 * bf2f(a0[j]) + p1 * bf2f(a1[j]) + p2 * bf2f(a2[j]);
    ((f4*)out)[i] = v;
}

extern "C" void kernel_launch(void* const* d_in, const int* in_sizes, int n_in,
                              void* d_out, int out_size, void* d_ws, size_t ws_size,
                              hipStream_t stream) {
    const float* queries = (const float*)d_in[0];
    const float* keys    = (const float*)d_in[1];
    const float* values  = (const float*)d_in[2];
    const float* hs      = (const float*)d_in[3];
    const float* W1      = (const float*)d_in[4];
    const float* b1      = (const float*)d_in[5];
    const float* ln_g    = (const float*)d_in[6];
    const float* ln_b    = (const float*)d_in[7];
    const float* W2      = (const float*)d_in[8];
    const float* b2      = (const float*)d_in[9];
    const float* hyp     = (const float*)d_in[10];
    const float* rn      = (const float*)d_in[11];
    float* out = (float*)d_out;
    char* ws = (char*)d_ws;

    const size_t MB = 1024ull * 1024ull;
    // qq16 occupies [0,12MB); MLP temporaries overlap it (all dead before k_attn)
    u16*   qq16 = (u16*)(ws);                   // 12 MB  [S,B,NH,T,HD] bf16
    u16*   hs_b = (u16*)(ws + 0 * MB);          //  4 MB  (dead after gemm1)
    u16*   w1_b = (u16*)(ws + 4 * MB);          //  2 MB  (dead after gemm1)
    u16*   w2_b = (u16*)(ws + 6 * MB);          //  2 MB  (dead after gemm2)
    float* X    = (float*)(ws + 8 * MB);        //  8 MB  (dead after lnrelu)
    u16*   xr   = (u16*)(ws + 16 * MB);         //  4 MB  (dead after gemm2)
    float* base = (float*)(ws + 24 * MB);       //  8 MB  (A5*que + CC*ctx)
    u16*   k_b  = (u16*)(ws + 32 * MB);         //  4 MB  (keys * 0.125, bf16)
    u16*   vt_b = (u16*)(ws + 36 * MB);         //  4 MB
    float* part = (float*)(ws + 40 * MB);       //  9 KB
    float* probs= (float*)(ws + 40 * MB + 65536);

    k_cvt4<<<6144, 256, 0, stream>>>(hs, hs_b, W1, w1_b, W2, w2_b, keys, k_b,
                                     out + 2097152);
    k_vtrans<<<dim3(16, 32), 256, 0, stream>>>(values, vt_b, out + 4194304);

    k_gemm_bt<0><<<dim3(16, 32), 256, 0, stream>>>(hs_b, w1_b, b1, nullptr, X);
    k_lnrelu<<<2048, 256, 0, stream>>>(X, ln_g, ln_b, xr);
    k_gemm_bt<1><<<dim3(16, 32), 256, 0, stream>>>(xr, w2_b, b2, queries, base);

    k_attn<<<768, 256, 0, stream>>>(base, hyp, rn, k_b, vt_b, qq16, part);
    k_finalize<<<1, 384, 0, stream>>>(part, probs);
    k_select<<<2048, 256, 0, stream>>>(qq16, probs, out);
}

// Round 10
// 167.388 us; speedup vs baseline: 1.1541x; 1.0171x over previous
//
#include <hip/hip_runtime.h>
#include <hip/hip_bf16.h>
#include <math.h>

#define NB 2
#define NHH 16
#define TT 1024
#define HDD 64
#define NSS 3
#define HH 1024

typedef float f4 __attribute__((ext_vector_type(4)));
typedef short bf16x8 __attribute__((ext_vector_type(8)));
typedef unsigned short u16;
typedef u16 u16x4 __attribute__((ext_vector_type(4)));

__device__ inline u16 f2bf(float f) {
    union { float f; unsigned u; } v; v.f = f;
    unsigned r = (v.u + 0x7FFFu + ((v.u >> 16) & 1u)) >> 16;
    return (u16)r;
}
__device__ inline float bf2f(u16 u) {
    union { unsigned u; float f; } v; v.u = ((unsigned)u) << 16;
    return v.f;
}
__device__ inline unsigned cvtpk(float lo, float hi) {
    unsigned r;
    asm("v_cvt_pk_bf16_f32 %0, %1, %2" : "=v"(r) : "v"(lo), "v"(hi));
    return r;
}
__device__ inline void gl_lds16(const u16* g, u16* l) {
    __builtin_amdgcn_global_load_lds(
        (const __attribute__((address_space(1))) unsigned int*)g,
        (__attribute__((address_space(3))) unsigned int*)l, 16, 0, 0);
}

__device__ inline float red16sum(float v) {
    v += __shfl_xor(v, 1);
    v += __shfl_xor(v, 2);
    v += __shfl_xor(v, 4);
    v += __shfl_xor(v, 8);
    return v;
}
__device__ inline float red64sum(float v) {
    v += __shfl_xor(v, 1);
    v += __shfl_xor(v, 2);
    v += __shfl_xor(v, 4);
    v += __shfl_xor(v, 8);
    v += __shfl_xor(v, 16);
    v += __shfl_xor(v, 32);
    return v;
}

// ---- fused prep: hs/W1/W2 -> bf16; keys -> swizzled tiles (x0.125) + passthrough;
// ---- V -> transposed swizzled tiles + passthrough.
// Tile image (shared with k_attn LDS): elem[row][col] bf16 at u16 offset
//   row*64 + ((col8 ^ (row&7))<<3) + (col&7),  col8 = col>>3, tile = 64x64.
__global__ __launch_bounds__(256) void k_prep(const float* __restrict__ hs, u16* __restrict__ hs_b,
                                              const float* __restrict__ W1, u16* __restrict__ w1_b,
                                              const float* __restrict__ W2, u16* __restrict__ w2_b,
                                              const float* __restrict__ keys, u16* __restrict__ k_b,
                                              float* __restrict__ outk,
                                              const float* __restrict__ V, u16* __restrict__ vt_b,
                                              float* __restrict__ outv) {
    __shared__ float tile[64][65];
    int b = blockIdx.x;
    if (b < 4096) {  // plain cvt: hs (2048), W1 (1024), W2 (1024)
        const float* s; u16* d; int base;
        if (b < 2048)      { s = hs; d = hs_b; base = 0; }
        else if (b < 3072) { s = W1; d = w1_b; base = 2048; }
        else               { s = W2; d = w2_b; base = 3072; }
        int i = (b - base) * 256 + threadIdx.x;
        f4 v = ((const f4*)s)[i];
        u16x4 o;
        o[0] = f2bf(v[0]); o[1] = f2bf(v[1]); o[2] = f2bf(v[2]); o[3] = f2bf(v[3]);
        ((u16x4*)d)[i] = o;
        return;
    }
    if (b < 5120) {  // keys -> swizzled tiles, scale 1/8; + passthrough copy
        int c = (b - 4096) * 256 + threadIdx.x;      // 8-float chunk id, [0, 262144)
        int bh = c >> 13, t = (c >> 3) & 1023, col8 = c & 7;
        int kt = t >> 6, row = t & 63;
        const float* sp = keys + (size_t)c * 8;
        f4 v0 = *(const f4*)(sp);
        f4 v1 = *(const f4*)(sp + 4);
        *(f4*)(outk + (size_t)c * 8) = v0;
        *(f4*)(outk + (size_t)c * 8 + 4) = v1;
        union { unsigned u[4]; int4 i4; } o;
        o.u[0] = cvtpk(v0[0] * 0.125f, v0[1] * 0.125f);
        o.u[1] = cvtpk(v0[2] * 0.125f, v0[3] * 0.125f);
        o.u[2] = cvtpk(v1[0] * 0.125f, v1[1] * 0.125f);
        o.u[3] = cvtpk(v1[2] * 0.125f, v1[3] * 0.125f);
        *(int4*)(k_b + (size_t)(bh * 16 + kt) * 4096 + row * 64 + ((col8 ^ (row & 7)) << 3)) = o.i4;
        return;
    }
    // V transpose -> swizzled tiles + passthrough
    int idx = b - 5120;                  // 512 = 32 bh x 16 tiles
    int bh = idx >> 4, kt = idx & 15, t0 = kt * 64;
    int r = threadIdx.x >> 2, c0 = (threadIdx.x & 3) * 16;
    const float* vp = V + ((size_t)bh * TT + t0) * HDD;
#pragma unroll
    for (int j = 0; j < 16; j += 4) {
        f4 v = *(const f4*)(vp + r * HDD + c0 + j);
        tile[r][c0 + j + 0] = v[0]; tile[r][c0 + j + 1] = v[1];
        tile[r][c0 + j + 2] = v[2]; tile[r][c0 + j + 3] = v[3];
        *(f4*)(outv + ((size_t)bh * TT + t0 + r) * HDD + c0 + j) = v;
    }
    __syncthreads();
    int d = threadIdx.x >> 2, x0 = (threadIdx.x & 3) * 16;
    u16* op = vt_b + (size_t)(bh * 16 + kt) * 4096 + d * 64;
#pragma unroll
    for (int cc = 0; cc < 2; ++cc) {     // two 8-col chunks: cols x0+cc*8 .. +7
        int c8 = (x0 >> 3) + cc;
        union { unsigned u[4]; int4 i4; } o;
#pragma unroll
        for (int p = 0; p < 4; ++p)
            o.u[p] = cvtpk(tile[c8 * 8 + 2 * p][d], tile[c8 * 8 + 2 * p + 1][d]);
        *(int4*)(op + ((c8 ^ (d & 7)) << 3)) = o.i4;
    }
}

// ---------------- GEMM: C[M,N] = A[M,K] * B[N,K]^T + bias ----------------
// EPI 0: out row-major [M,N] bf16.
// EPI 1: out = A5*que + CC*(acc+bias) scattered to [B,NH,T,HD] fp32 (PCN base).
template <int EPI>
__global__ __launch_bounds__(256) void k_gemm_bt(const u16* __restrict__ A,
                                                 const u16* __restrict__ Bm,
                                                 const float* __restrict__ bias,
                                                 const float* __restrict__ que,
                                                 void* __restrict__ outv) {
    const int K = 1024, N = 1024;
    int w = threadIdx.x >> 6, l = threadIdx.x & 63, lr = l & 15, lg = l >> 4;
    int m0 = blockIdx.y * 64 + w * 16;
    int n0 = blockIdx.x * 64;
    const u16* ap = A + (size_t)(m0 + lr) * K + lg * 8;
    const u16* bp = Bm + (size_t)(n0 + lr) * K + lg * 8;
    f4 z4 = {0.f, 0.f, 0.f, 0.f};
    f4 acc[4] = {z4, z4, z4, z4};
#pragma unroll 2
    for (int kk = 0; kk < K; kk += 32) {
        bf16x8 a  = *(const bf16x8*)(ap + kk);
        bf16x8 b0 = *(const bf16x8*)(bp + kk);
        bf16x8 b1 = *(const bf16x8*)(bp + 16 * K + kk);
        bf16x8 b2 = *(const bf16x8*)(bp + 32 * K + kk);
        bf16x8 b3 = *(const bf16x8*)(bp + 48 * K + kk);
        acc[0] = __builtin_amdgcn_mfma_f32_16x16x32_bf16(a, b0, acc[0], 0, 0, 0);
        acc[1] = __builtin_amdgcn_mfma_f32_16x16x32_bf16(a, b1, acc[1], 0, 0, 0);
        acc[2] = __builtin_amdgcn_mfma_f32_16x16x32_bf16(a, b2, acc[2], 0, 0, 0);
        acc[3] = __builtin_amdgcn_mfma_f32_16x16x32_bf16(a, b3, acc[3], 0, 0, 0);
    }
    const float A5 = 0.9509900499f, CC = 1.0f - A5;
#pragma unroll
    for (int cf = 0; cf < 4; ++cf) {
        int col = n0 + cf * 16 + lr;
        float bs = bias[col];
#pragma unroll
        for (int r = 0; r < 4; ++r) {
            int row = m0 + lg * 4 + r;
            float v = acc[cf][r] + bs;
            if (EPI == 0) {
                ((u16*)outv)[(size_t)row * N + col] = f2bf(v);
            } else {
                int b = row >> 10, t = row & 1023, nh = col >> 6, hd = col & 63;
                size_t oidx = (((size_t)(b * NHH + nh)) * TT + t) * HDD + hd;
                ((float*)outv)[oidx] = A5 * que[oidx] + CC * v;
            }
        }
    }
}

// ---------------- LayerNorm + ReLU (bf16 in) -> bf16 ----------------
__global__ __launch_bounds__(256) void k_lnrelu(const u16* __restrict__ X,
                                                const float* __restrict__ g,
                                                const float* __restrict__ bta,
                                                u16* __restrict__ xr) {
    int row = blockIdx.x;
    u16x4 xv = ((const u16x4*)(X + (size_t)row * HH))[threadIdx.x];
    f4 v;
    v[0] = bf2f(xv[0]); v[1] = bf2f(xv[1]); v[2] = bf2f(xv[2]); v[3] = bf2f(xv[3]);
    float s = v[0] + v[1] + v[2] + v[3];
    float s2 = v[0] * v[0] + v[1] * v[1] + v[2] * v[2] + v[3] * v[3];
    s = red64sum(s);
    s2 = red64sum(s2);
    __shared__ float red[8];
    int w = threadIdx.x >> 6, l = threadIdx.x & 63;
    if (l == 0) { red[w] = s; red[w + 4] = s2; }
    __syncthreads();
    float S1 = red[0] + red[1] + red[2] + red[3];
    float S2 = red[4] + red[5] + red[6] + red[7];
    float mu = S1 * (1.0f / 1024.0f);
    float var = S2 * (1.0f / 1024.0f) - mu * mu;
    float rstd = rsqrtf(var + 1e-5f);
    f4 gv = ((const f4*)g)[threadIdx.x];
    f4 bv = ((const f4*)bta)[threadIdx.x];
    u16x4 o;
#pragma unroll
    for (int j = 0; j < 4; ++j) {
        float y = (v[j] - mu) * rstd * gv[j] + bv[j];
        y = fmaxf(y, 0.f);
        o[j] = f2bf(y);
    }
    ((u16x4*)(xr + (size_t)row * HH))[threadIdx.x] = o;
}

// ------- fused q-formation + flash attention + energy stats -------
// 128 q-rows/block, 768 blocks (3/CU), XCD-colocated per (b,h) (bi%32).
// K/V staged by global_load_lds(16B) from pre-swizzled tiles (k_prep layout),
// double-buffered, ONE barrier per kt. q formed coalesced into swizzled LDS
// slab (reusing P-tile space) + qq global. P packed via v_cvt_pk_bf16_f32.
// align from QK diagonal. Max-free softmax (|s|<~15 bounded; exp fits fp32).
__global__ __launch_bounds__(256, 3) void k_attn(const float* __restrict__ basep_,
                                                 const float* __restrict__ hyp,
                                                 const float* __restrict__ rn,
                                                 const u16* __restrict__ Kb,
                                                 const u16* __restrict__ Vt,
                                                 u16* __restrict__ qq,
                                                 float* __restrict__ part) {
    int bi = blockIdx.x;
    int p_ = bi & 31, j_ = bi >> 5;      // XCD swizzle: same (b,h) -> same XCD
    int h = p_ & 15, b = p_ >> 4;
    int s = j_ >> 3, qt2 = j_ & 7;
    int sb = s * 2 + b;
    int bh = b * NHH + h;
    int pi = sb * 128 + h * 8 + qt2;
    int w = threadIdx.x >> 6, l = threadIdx.x & 63, lr = l & 15, lg = l >> 4;
    int t0 = qt2 * 128;
    f4 z4 = {0.f, 0.f, 0.f, 0.f};

    __shared__ u16 Ks[2][4096];     // swizzled 64x64 tile images, double-buffered
    __shared__ u16 Vs[2][4096];
    __shared__ u16 plds[8][1024];   // q-slab (prologue) then per-wave P tiles

    const u16* kT = Kb + (size_t)(bh * 16) * 4096;   // 16 tiles of this (b,h)
    const u16* vT = Vt + (size_t)(bh * 16) * 4096;

    // stage tile 0 (in flight during q formation)
#pragma unroll
    for (int j = 0; j < 2; ++j) {
        int co = (w + 4 * j) * 512;
        gl_lds16(kT + co + l * 8, &Ks[0][co]);
        gl_lds16(vT + co + l * 8, &Vs[0][co]);
    }

    // ---- coalesced q formation -> LDS slab + qq global ----
    const float CH = 0.1f * 0.9509900499f;
    const float C0 = 0.0096059601f, C1 = 0.0097029900f, C2 = 0.0098010000f, C3 = 0.0099f;
    const float* basep = basep_ + ((size_t)bh * TT) * HDD;
    const float* hypp = hyp + ((size_t)(sb * NHH + h) * TT) * HDD;
    const float* rn0p = rn + ((size_t)(((s * 4 + 0) * 2 + b) * NHH + h) * TT) * HDD;
    const float* rn1p = rn + ((size_t)(((s * 4 + 1) * 2 + b) * NHH + h) * TT) * HDD;
    const float* rn2p = rn + ((size_t)(((s * 4 + 2) * 2 + b) * NHH + h) * TT) * HDD;
    const float* rn3p = rn + ((size_t)(((s * 4 + 3) * 2 + b) * NHH + h) * TT) * HDD;
    u16* qqp = qq + ((size_t)(sb * NHH + h) * TT) * HDD;

    char* slab = (char*)&plds[0][0];
    {
        int t = threadIdx.x;
#pragma unroll
        for (int m = 0; m < 4; ++m) {
            int j = t + 256 * m;                     // 16B bf16 chunk id in [0,1024)
            size_t off = (size_t)t0 * HDD + (size_t)j * 8;
            f4 a0 = *(const f4*)(basep + off);
            f4 a1 = *(const f4*)(basep + off + 4);
            a0 += CH * __builtin_nontemporal_load((const f4*)(hypp + off));
            a1 += CH * __builtin_nontemporal_load((const f4*)(hypp + off + 4));
            a0 += C0 * __builtin_nontemporal_load((const f4*)(rn0p + off));
            a1 += C0 * __builtin_nontemporal_load((const f4*)(rn0p + off + 4));
            a0 += C1 * __builtin_nontemporal_load((const f4*)(rn1p + off));
            a1 += C1 * __builtin_nontemporal_load((const f4*)(rn1p + off + 4));
            a0 += C2 * __builtin_nontemporal_load((const f4*)(rn2p + off));
            a1 += C2 * __builtin_nontemporal_load((const f4*)(rn2p + off + 4));
            a0 += C3 * __builtin_nontemporal_load((const f4*)(rn3p + off));
            a1 += C3 * __builtin_nontemporal_load((const f4*)(rn3p + off + 4));
            union { unsigned u[4]; int4 i4; } o;
            o.u[0] = cvtpk(a0[0], a0[1]); o.u[1] = cvtpk(a0[2], a0[3]);
            o.u[2] = cvtpk(a1[0], a1[1]); o.u[3] = cvtpk(a1[2], a1[3]);
            int row = j >> 3, slot = j & 7;
            *(int4*)(slab + row * 128 + (((slot ^ (row & 7))) << 4)) = o.i4;
            *(int4*)(qqp + (size_t)t0 * HDD + (size_t)j * 8) = o.i4;  // coalesced
        }
    }
    __syncthreads();   // drains gl_lds tile0 + slab writes

    // frag reads: each wave reads only its own slab quarter (rows w*32..+31)
    bf16x8 aq[2][2];
#pragma unroll
    for (int qr = 0; qr < 2; ++qr) {
        int r_ = w * 32 + qr * 16 + lr;
#pragma unroll
        for (int c = 0; c < 2; ++c)
            aq[qr][c] = *(const bf16x8*)(slab + r_ * 128 + (((c * 4 + lg) ^ (r_ & 7)) << 4));
    }

    f4 acco[2][4] = {{z4, z4, z4, z4}, {z4, z4, z4, z4}};
    float zrow[2][4] = {{0.f, 0.f, 0.f, 0.f}, {0.f, 0.f, 0.f, 0.f}};
    float wrow[2][4] = {{0.f, 0.f, 0.f, 0.f}, {0.f, 0.f, 0.f, 0.f}};
    float al_lane = 0.f;
    int kdiag = qt2 * 2 + (w >> 1);   // kt holding this wave's diagonal elements

    for (int kt = 0; kt < 16; ++kt) {
        int cur = kt & 1;
        if (kt < 15) {  // issue next-tile direct-to-LDS loads; land by the barrier
#pragma unroll
            for (int j = 0; j < 2; ++j) {
                int co = (w + 4 * j) * 512;
                gl_lds16(kT + (kt + 1) * 4096 + co + l * 8, &Ks[cur ^ 1][co]);
                gl_lds16(vT + (kt + 1) * 4096 + co + l * 8, &Vs[cur ^ 1][co]);
            }
        }
        char* KsB = (char*)Ks[cur];
        char* VsB = (char*)Vs[cur];

        // QK^T: K frags shared across both row-frags
        f4 sc[2][4];
        __builtin_amdgcn_s_setprio(1);
#pragma unroll
        for (int cf = 0; cf < 4; ++cf) {
            int row = cf * 16 + lr, rs = row & 7;
            bf16x8 bk0 = *(const bf16x8*)(KsB + row * 128 + ((lg ^ rs) << 4));
            bf16x8 bk1 = *(const bf16x8*)(KsB + row * 128 + (((4 + lg) ^ rs) << 4));
            f4 t0a = __builtin_amdgcn_mfma_f32_16x16x32_bf16(aq[0][0], bk0, z4, 0, 0, 0);
            sc[0][cf] = __builtin_amdgcn_mfma_f32_16x16x32_bf16(aq[0][1], bk1, t0a, 0, 0, 0);
            f4 t1a = __builtin_amdgcn_mfma_f32_16x16x32_bf16(aq[1][0], bk0, z4, 0, 0, 0);
            sc[1][cf] = __builtin_amdgcn_mfma_f32_16x16x32_bf16(aq[1][1], bk1, t1a, 0, 0, 0);
        }
        __builtin_amdgcn_s_setprio(0);

        // align from diagonal: row L = w*32+qr*16+lg*4+r meets col k at
        // kt==kdiag, cf=(2w+qr)&3, on lanes lr==lg*4+r. S has 1/8 scale -> x8.
        if (kt == kdiag) {
            f4 sd0 = (w & 1) ? sc[0][2] : sc[0][0];
            f4 sd1 = (w & 1) ? sc[1][3] : sc[1][1];
            int rr = lr & 3;
            float e0 = rr == 0 ? sd0[0] : (rr == 1 ? sd0[1] : (rr == 2 ? sd0[2] : sd0[3]));
            float e1 = rr == 0 ? sd1[0] : (rr == 1 ? sd1[1] : (rr == 2 ? sd1[2] : sd1[3]));
            if (lg == (lr >> 2)) al_lane += (e0 + e1) * 8.0f;
        }

        // softmax partials (m=0) + P -> per-wave LDS bf16 (cvt_pk packed)
#pragma unroll
        for (int qr = 0; qr < 2; ++qr) {
            u16* pl = &plds[w * 2 + qr][0];
#pragma unroll
            for (int cf = 0; cf < 4; ++cf) {
                float p0 = __expf(sc[qr][cf][0]);
                float p1 = __expf(sc[qr][cf][1]);
                float p2 = __expf(sc[qr][cf][2]);
                float p3 = __expf(sc[qr][cf][3]);
                zrow[qr][0] += p0; zrow[qr][1] += p1;
                zrow[qr][2] += p2; zrow[qr][3] += p3;
                wrow[qr][0] = fmaf(p0, sc[qr][cf][0], wrow[qr][0]);
                wrow[qr][1] = fmaf(p1, sc[qr][cf][1], wrow[qr][1]);
                wrow[qr][2] = fmaf(p2, sc[qr][cf][2], wrow[qr][2]);
                wrow[qr][3] = fmaf(p3, sc[qr][cf][3], wrow[qr][3]);
                unsigned pa01 = cvtpk(p0, p1), pa23 = cvtpk(p2, p3);
                int base_ = cf * 16 + lr;
                pl[(((lg * 4 + 0) * 64 + base_)) ^ (((lg * 4 + 0) & 7) << 3)] = (u16)pa01;
                pl[(((lg * 4 + 1) * 64 + base_)) ^ (((lg * 4 + 1) & 7) << 3)] = (u16)(pa01 >> 16);
                pl[(((lg * 4 + 2) * 64 + base_)) ^ (((lg * 4 + 2) & 7) << 3)] = (u16)pa23;
                pl[(((lg * 4 + 3) * 64 + base_)) ^ (((lg * 4 + 3) & 7) << 3)] = (u16)(pa23 >> 16);
            }
        }
        bf16x8 pa[2][2];
#pragma unroll
        for (int qr = 0; qr < 2; ++qr) {
            const u16* pl = &plds[w * 2 + qr][0];
            pa[qr][0] = *(const bf16x8*)&pl[(lr * 64 + lg * 8) ^ ((lr & 7) << 3)];
            pa[qr][1] = *(const bf16x8*)&pl[(lr * 64 + 32 + lg * 8) ^ ((lr & 7) << 3)];
        }
        // PV: V frags shared across both row-frags
        __builtin_amdgcn_s_setprio(1);
#pragma unroll
        for (int cf = 0; cf < 4; ++cf) {
            int row = cf * 16 + lr, rs = row & 7;
            bf16x8 bv0 = *(const bf16x8*)(VsB + row * 128 + ((lg ^ rs) << 4));
            bf16x8 bv1 = *(const bf16x8*)(VsB + row * 128 + (((4 + lg) ^ rs) << 4));
            acco[0][cf] = __builtin_amdgcn_mfma_f32_16x16x32_bf16(pa[0][0], bv0, acco[0][cf], 0, 0, 0);
            acco[0][cf] = __builtin_amdgcn_mfma_f32_16x16x32_bf16(pa[0][1], bv1, acco[0][cf], 0, 0, 0);
            acco[1][cf] = __builtin_amdgcn_mfma_f32_16x16x32_bf16(pa[1][0], bv0, acco[1][cf], 0, 0, 0);
            acco[1][cf] = __builtin_amdgcn_mfma_f32_16x16x32_bf16(pa[1][1], bv1, acco[1][cf], 0, 0, 0);
        }
        __builtin_amdgcn_s_setprio(0);

        __syncthreads();   // single barrier per kt (drains next-tile gl_lds too)
    }

    // per-row finalize: out_mag & entropy (m = 0)
    float magw = 0.f, entw = 0.f;
#pragma unroll
    for (int qr = 0; qr < 2; ++qr) {
#pragma unroll
        for (int r = 0; r < 4; ++r) {
            float zz = red16sum(zrow[qr][r]);
            float ww = red16sum(wrow[qr][r]);
            float ssq = acco[qr][0][r] * acco[qr][0][r] + acco[qr][1][r] * acco[qr][1][r] +
                        acco[qr][2][r] * acco[qr][2][r] + acco[qr][3][r] * acco[qr][3][r];
            ssq = red16sum(ssq);
            float inv = 1.0f / zz;
            magw += sqrtf(ssq) * inv;
            entw += __logf(zz) - ww * inv;
        }
    }
    magw += __shfl_xor(magw, 16); magw += __shfl_xor(magw, 32);
    entw += __shfl_xor(entw, 16); entw += __shfl_xor(entw, 32);
    float al = red64sum(al_lane);

    __shared__ float red[4][3];
    if (l == 0) { red[w][0] = magw; red[w][1] = entw; red[w][2] = al; }
    __syncthreads();
    if (threadIdx.x == 0) {
        part[pi * 3 + 0] = red[0][0] + red[1][0] + red[2][0] + red[3][0];
        part[pi * 3 + 1] = red[0][1] + red[1][1] + red[2][1] + red[3][1];
        part[pi * 3 + 2] = red[0][2] + red[1][2] + red[2][2] + red[3][2];
    }
}

// ---------------- energy reduce + softmax over samples ----------------
__global__ void k_finalize(const float* __restrict__ part, float* __restrict__ probs) {
    int w = threadIdx.x >> 6, l = threadIdx.x & 63;
    __shared__ float eng[6];
    if (w < 6) {
        float a0 = 0.f, a1 = 0.f, a2 = 0.f;
        for (int i = l; i < 128; i += 64) {
            const float* pp = part + (size_t)(w * 128 + i) * 3;
            a0 += pp[0]; a1 += pp[1]; a2 += pp[2];
        }
        a0 = red64sum(a0); a1 = red64sum(a1); a2 = red64sum(a2);
        if (l == 0) {
            const float inv = 1.0f / 16384.0f;
            eng[w] = a0 * inv - 0.1f * (a1 * inv) - 0.05f * (a2 * inv);
        }
    }
    __syncthreads();
    if (threadIdx.x < 2) {
        int b = threadIdx.x;
        float e0 = -eng[0 + b], e1 = -eng[2 + b], e2 = -eng[4 + b];
        float mx = fmaxf(e0, fmaxf(e1, e2));
        float x0 = __expf(e0 - mx), x1 = __expf(e1 - mx), x2 = __expf(e2 - mx);
        float inv = 1.0f / (x0 + x1 + x2);
        probs[0 + b] = x0 * inv;
        probs[2 + b] = x1 * inv;
        probs[4 + b] = x2 * inv;
    }
}

// ---------------- selected = sum_s probs[s,b]*q[s] (q in bf16) ----------------
__global__ __launch_bounds__(256) void k_select(const u16* __restrict__ qq,
                                                const float* __restrict__ probs,
                                                float* __restrict__ out) {
    const int NQ4 = 524288;               // u16x4 groups per sample
    int i = blockIdx.x * 256 + threadIdx.x;
    int b = i >> 18;                      // 262144 groups per batch
    float p0 = probs[0 + b], p1 = probs[2 + b], p2 = probs[4 + b];
    u16x4 a0 = ((const u16x4*)qq)[i];
    u16x4 a1 = ((const u16x4*)qq)[NQ4 + i];
    u16x4 a2 = ((const u16x4*)qq)[2 * NQ4 + i];
    f4 v;
#pragma unroll
    for (int j = 0; j < 4; ++j)
        v[j] = p0 * bf2f(a0[j]) + p1 * bf2f(a1[j]) + p2 * bf2f(a2[j]);
    ((f4*)out)[i] = v;
}

extern "C" void kernel_launch(void* const* d_in, const int* in_sizes, int n_in,
                              void* d_out, int out_size, void* d_ws, size_t ws_size,
                              hipStream_t stream) {
    const float* queries = (const float*)d_in[0];
    const float* keys    = (const float*)d_in[1];
    const float* values  = (const float*)d_in[2];
    const float* hs      = (const float*)d_in[3];
    const float* W1      = (const float*)d_in[4];
    const float* b1      = (const float*)d_in[5];
    const float* ln_g    = (const float*)d_in[6];
    const float* ln_b    = (const float*)d_in[7];
    const float* W2      = (const float*)d_in[8];
    const float* b2      = (const float*)d_in[9];
    const float* hyp     = (const float*)d_in[10];
    const float* rn      = (const float*)d_in[11];
    float* out = (float*)d_out;
    char* ws = (char*)d_ws;

    const size_t MB = 1024ull * 1024ull;
    // qq16 occupies [0,12MB); MLP temporaries overlap it (all dead before k_attn)
    u16*   qq16 = (u16*)(ws);                   // 12 MB  [S,B,NH,T,HD] bf16
    u16*   hs_b = (u16*)(ws + 0 * MB);          //  4 MB  (dead after gemm1)
    u16*   w1_b = (u16*)(ws + 4 * MB);          //  2 MB  (dead after gemm1)
    u16*   w2_b = (u16*)(ws + 6 * MB);          //  2 MB  (dead after gemm2)
    u16*   X    = (u16*)(ws + 8 * MB);          //  4 MB  bf16 (dead after lnrelu)
    u16*   xr   = (u16*)(ws + 16 * MB);         //  4 MB  (dead after gemm2)
    float* base = (float*)(ws + 24 * MB);       //  8 MB  (A5*que + CC*ctx)
    u16*   k_b  = (u16*)(ws + 32 * MB);         //  4 MB  swizzled tiles, keys*0.125
    u16*   vt_b = (u16*)(ws + 36 * MB);         //  4 MB  swizzled transposed tiles
    float* part = (float*)(ws + 40 * MB);       //  9 KB
    float* probs= (float*)(ws + 40 * MB + 65536);

    k_prep<<<5632, 256, 0, stream>>>(hs, hs_b, W1, w1_b, W2, w2_b,
                                     keys, k_b, out + 2097152,
                                     values, vt_b, out + 4194304);

    k_gemm_bt<0><<<dim3(16, 32), 256, 0, stream>>>(hs_b, w1_b, b1, nullptr, X);
    k_lnrelu<<<2048, 256, 0, stream>>>(X, ln_g, ln_b, xr);
    k_gemm_bt<1><<<dim3(16, 32), 256, 0, stream>>>(xr, w2_b, b2, queries, base);

    k_attn<<<768, 256, 0, stream>>>(base, hyp, rn, k_b, vt_b, qq16, part);
    k_finalize<<<1, 384, 0, stream>>>(part, probs);
    k_select<<<2048, 256, 0, stream>>>(qq16, probs, out);
}